// Round 1
// baseline (2929.190 us; speedup 1.0000x reference)
//
#include <hip/hip_runtime.h>
#include <math.h>

// Problem constants
constexpr int Tq  = 4096;   // sequence length
constexpr int D   = 1024;   // model dim
constexpr int H   = 16;     // query heads
constexpr int HKV = 4;      // kv heads
constexpr int HD  = 64;     // head dim
constexpr int KVD = HKV * HD;        // 256
constexpr int NQKV = D + 2 * KVD;    // 1536

// ---------------------------------------------------------------------------
// GEMM: C[M,N] = A[M,K] * B[N,K]^T   (f32, 64x64 tile, BK=16, 256 thr, 4x4/thr)
// ---------------------------------------------------------------------------
__global__ __launch_bounds__(256)
void gemm_qkv(const float* __restrict__ A, const float* __restrict__ B,
              float* __restrict__ qb, float* __restrict__ kb, float* __restrict__ vb)
{
    __shared__ float As[16][65];
    __shared__ float Bs[16][65];
    const int K = D;
    const int tid = threadIdx.x;
    const int ty = tid >> 4, tx = tid & 15;
    const int m0 = blockIdx.x * 64;
    const int n0 = blockIdx.y * 64;

    float acc[4][4] = {};

    for (int k0 = 0; k0 < K; k0 += 16) {
        {
            const int m = tid >> 2, kq = (tid & 3) * 4;
            float4 av = *(const float4*)(A + (size_t)(m0 + m) * K + k0 + kq);
            As[kq + 0][m] = av.x; As[kq + 1][m] = av.y;
            As[kq + 2][m] = av.z; As[kq + 3][m] = av.w;
            float4 bv = *(const float4*)(B + (size_t)(n0 + m) * K + k0 + kq);
            Bs[kq + 0][m] = bv.x; Bs[kq + 1][m] = bv.y;
            Bs[kq + 2][m] = bv.z; Bs[kq + 3][m] = bv.w;
        }
        __syncthreads();
        #pragma unroll
        for (int kk = 0; kk < 16; ++kk) {
            float a[4], b[4];
            #pragma unroll
            for (int i = 0; i < 4; ++i) a[i] = As[kk][ty * 4 + i];
            #pragma unroll
            for (int j = 0; j < 4; ++j) b[j] = Bs[kk][tx * 4 + j];
            #pragma unroll
            for (int i = 0; i < 4; ++i)
                #pragma unroll
                for (int j = 0; j < 4; ++j)
                    acc[i][j] += a[i] * b[j];
        }
        __syncthreads();
    }

    // scatter into q/k/v buffers laid out [head][t][d]
    #pragma unroll
    for (int i = 0; i < 4; ++i) {
        const int t = m0 + ty * 4 + i;
        #pragma unroll
        for (int j = 0; j < 4; ++j) {
            const int jj = n0 + tx * 4 + j;
            const int d = jj & 63;
            const float v = acc[i][j];
            if (jj < D) {
                qb[((size_t)(jj >> 6) * Tq + t) * HD + d] = v;
            } else if (jj < D + KVD) {
                kb[((size_t)((jj - D) >> 6) * Tq + t) * HD + d] = v;
            } else {
                vb[((size_t)((jj - D - KVD) >> 6) * Tq + t) * HD + d] = v;
            }
        }
    }
}

__global__ __launch_bounds__(256)
void gemm_proj(const float* __restrict__ A, const float* __restrict__ B,
               float* __restrict__ C)
{
    __shared__ float As[16][65];
    __shared__ float Bs[16][65];
    const int K = D;
    const int tid = threadIdx.x;
    const int ty = tid >> 4, tx = tid & 15;
    const int m0 = blockIdx.x * 64;
    const int n0 = blockIdx.y * 64;

    float acc[4][4] = {};

    for (int k0 = 0; k0 < K; k0 += 16) {
        {
            const int m = tid >> 2, kq = (tid & 3) * 4;
            float4 av = *(const float4*)(A + (size_t)(m0 + m) * K + k0 + kq);
            As[kq + 0][m] = av.x; As[kq + 1][m] = av.y;
            As[kq + 2][m] = av.z; As[kq + 3][m] = av.w;
            float4 bv = *(const float4*)(B + (size_t)(n0 + m) * K + k0 + kq);
            Bs[kq + 0][m] = bv.x; Bs[kq + 1][m] = bv.y;
            Bs[kq + 2][m] = bv.z; Bs[kq + 3][m] = bv.w;
        }
        __syncthreads();
        #pragma unroll
        for (int kk = 0; kk < 16; ++kk) {
            float a[4], b[4];
            #pragma unroll
            for (int i = 0; i < 4; ++i) a[i] = As[kk][ty * 4 + i];
            #pragma unroll
            for (int j = 0; j < 4; ++j) b[j] = Bs[kk][tx * 4 + j];
            #pragma unroll
            for (int i = 0; i < 4; ++i)
                #pragma unroll
                for (int j = 0; j < 4; ++j)
                    acc[i][j] += a[i] * b[j];
        }
        __syncthreads();
    }

    #pragma unroll
    for (int i = 0; i < 4; ++i) {
        const int t = m0 + ty * 4 + i;
        #pragma unroll
        for (int j = 0; j < 4; ++j) {
            C[(size_t)t * D + n0 + tx * 4 + j] = acc[i][j];
        }
    }
}

// ---------------------------------------------------------------------------
// Per-row (t, head) RMS norm + rotary + gain.  One 64-lane wave per row.
// Rows 0..H*Tq-1 are Q rows; rows H*Tq..(H+HKV)*Tq-1 are K rows.
// ---------------------------------------------------------------------------
__global__ __launch_bounds__(256)
void norm_rope(float* __restrict__ qb, float* __restrict__ kb,
               const float* __restrict__ gain)
{
    const int tid  = threadIdx.x;
    const int lane = tid & 63;
    const long row = (long)blockIdx.x * 4 + (tid >> 6);
    const long QROWS = (long)H * Tq;

    float* base;
    int t;
    float g;
    if (row < QROWS) {
        base = qb + row * HD;
        t = (int)(row & (Tq - 1));
        g = gain[row >> 12];           // h = row / Tq (Tq = 2^12)
    } else {
        const long r2 = row - QROWS;
        base = kb + r2 * HD;
        t = (int)(r2 & (Tq - 1));
        g = 1.0f;
    }

    float v = base[lane];
    float ss = v * v;
    #pragma unroll
    for (int m = 1; m < 64; m <<= 1) ss += __shfl_xor(ss, m);
    const float rms = rsqrtf(ss * (1.0f / 64.0f) + 1.1920929e-07f);
    const float vn = v * rms;
    const float p = __shfl_xor(vn, 32);

    const int i = lane & 31;
    // inv_freq = 10000^(-i/32) = exp(-i * ln(10000)/32)
    const float invf = __expf((float)i * -0.28782313662425572f);
    const float ang = (float)t * invf;
    float s, c;
    sincosf(ang, &s, &c);   // accurate range reduction (angles up to ~4095 rad)
    const float res = vn * c + ((lane < 32) ? p * s : -(p * s));
    base[lane] = res * g;
}

// ---------------------------------------------------------------------------
// Flash attention (online softmax), f32.  Block = (q-tile of 64 rows, head).
// 256 threads: thread = (row r = tid>>2, col-group c0 = (tid&3)*16).
// Q row in registers; K/V/P tiles in LDS (padded to avoid bank conflicts).
// ---------------------------------------------------------------------------
__global__ __launch_bounds__(256)
void attn(const float* __restrict__ qb, const float* __restrict__ kb,
          const float* __restrict__ vb, float* __restrict__ yb)
{
    __shared__ float Ks[64][65];
    __shared__ float Ps[64][65];
    __shared__ float Vs[64][64];

    const int qt  = blockIdx.x;
    const int h   = blockIdx.y;
    const int hkv = h >> 2;
    const int tid = threadIdx.x;
    const int r   = tid >> 2;
    const int c0  = (tid & 3) * 16;
    const int qg  = qt * 64 + r;

    // Q row -> registers (4 threads per row load the same row; L1 absorbs it)
    const float* qrow = qb + ((size_t)h * Tq + qg) * HD;
    float4 qreg[16];
    #pragma unroll
    for (int i = 0; i < 16; ++i) qreg[i] = *(const float4*)(qrow + i * 4);

    float4 o[4];
    #pragma unroll
    for (int i = 0; i < 4; ++i) o[i] = make_float4(0.f, 0.f, 0.f, 0.f);
    float mrow  = -INFINITY;
    float lpart = 0.f;

    for (int kt = 0; kt <= qt; ++kt) {
        __syncthreads();   // previous iteration's P/V reads complete
        {
            int l = tid;
            #pragma unroll
            for (int it = 0; it < 4; ++it, l += 256) {
                const int row = l >> 4, c4 = (l & 15) * 4;
                const size_t src = ((size_t)hkv * Tq + kt * 64 + row) * HD + c4;
                float4 kv = *(const float4*)(kb + src);
                Ks[row][c4 + 0] = kv.x; Ks[row][c4 + 1] = kv.y;
                Ks[row][c4 + 2] = kv.z; Ks[row][c4 + 3] = kv.w;
                float4 vv = *(const float4*)(vb + src);
                *(float4*)&Vs[row][c4] = vv;
            }
        }
        __syncthreads();

        // S = Q K^T for this thread's 16 columns
        float sv[16];
        float mloc = -INFINITY;
        #pragma unroll
        for (int cc = 0; cc < 16; ++cc) {
            const int c = c0 + cc;
            float s = 0.f;
            #pragma unroll
            for (int d4 = 0; d4 < 16; ++d4) {
                const float4 q = qreg[d4];
                s += q.x * Ks[c][d4 * 4 + 0];
                s += q.y * Ks[c][d4 * 4 + 1];
                s += q.z * Ks[c][d4 * 4 + 2];
                s += q.w * Ks[c][d4 * 4 + 3];
            }
            s *= 0.125f;                       // 1/sqrt(64)
            if (kt * 64 + c > qg) s = -INFINITY;  // causal mask
            sv[cc] = s;
            mloc = fmaxf(mloc, s);
        }
        // row max across the 4 lanes sharing this row
        mloc = fmaxf(mloc, __shfl_xor(mloc, 1));
        mloc = fmaxf(mloc, __shfl_xor(mloc, 2));
        const float mnew  = fmaxf(mrow, mloc);
        const float alpha = __expf(mrow - mnew);   // exp(-inf)=0 on first tile
        lpart *= alpha;
        #pragma unroll
        for (int i = 0; i < 4; ++i) {
            o[i].x *= alpha; o[i].y *= alpha; o[i].z *= alpha; o[i].w *= alpha;
        }
        #pragma unroll
        for (int cc = 0; cc < 16; ++cc) {
            const float p = __expf(sv[cc] - mnew);
            lpart += p;
            Ps[r][c0 + cc] = p;
        }
        mrow = mnew;
        __syncthreads();   // P visible to all lanes of the row's wave

        // O += P V  (this thread's 16 output dims c0..c0+15)
        #pragma unroll 16
        for (int kk = 0; kk < 64; ++kk) {
            const float p = Ps[r][kk];
            const float4 v0 = *(const float4*)&Vs[kk][c0 + 0];
            const float4 v1 = *(const float4*)&Vs[kk][c0 + 4];
            const float4 v2 = *(const float4*)&Vs[kk][c0 + 8];
            const float4 v3 = *(const float4*)&Vs[kk][c0 + 12];
            o[0].x += p * v0.x; o[0].y += p * v0.y; o[0].z += p * v0.z; o[0].w += p * v0.w;
            o[1].x += p * v1.x; o[1].y += p * v1.y; o[1].z += p * v1.z; o[1].w += p * v1.w;
            o[2].x += p * v2.x; o[2].y += p * v2.y; o[2].z += p * v2.z; o[2].w += p * v2.w;
            o[3].x += p * v3.x; o[3].y += p * v3.y; o[3].z += p * v3.z; o[3].w += p * v3.w;
        }
    }

    float l = lpart + __shfl_xor(lpart, 1);
    l += __shfl_xor(l, 2);
    const float inv = 1.0f / l;

    // write y in [t][h*64+d] layout so the proj GEMM reads it directly
    float* yrow = yb + (size_t)qg * D + h * HD + c0;
    #pragma unroll
    for (int i = 0; i < 4; ++i) {
        float4 w = o[i];
        w.x *= inv; w.y *= inv; w.z *= inv; w.w *= inv;
        *(float4*)(yrow + i * 4) = w;
    }
}

// ---------------------------------------------------------------------------
extern "C" void kernel_launch(void* const* d_in, const int* in_sizes, int n_in,
                              void* d_out, int out_size, void* d_ws, size_t ws_size,
                              hipStream_t stream)
{
    const float* x      = (const float*)d_in[0];   // [1, 4096, 1024]
    const float* w_qkv  = (const float*)d_in[1];   // [1536, 1024]
    const float* w_proj = (const float*)d_in[2];   // [1024, 1024]
    const float* q_gain = (const float*)d_in[3];   // [16]
    float* out = (float*)d_out;                    // [4096, 1024]

    // workspace layout (f32): qbuf 16MB | kbuf 4MB | vbuf 4MB | ybuf 16MB
    float* qb = (float*)d_ws;
    float* kb = qb + (size_t)H * Tq * HD;
    float* vb = kb + (size_t)HKV * Tq * HD;
    float* yb = vb + (size_t)HKV * Tq * HD;

    gemm_qkv<<<dim3(Tq / 64, NQKV / 64), 256, 0, stream>>>(x, w_qkv, qb, kb, vb);
    norm_rope<<<dim3((H + HKV) * Tq / 4), 256, 0, stream>>>(qb, kb, q_gain);
    attn<<<dim3(Tq / 64, H), 256, 0, stream>>>(qb, kb, vb, yb);
    gemm_proj<<<dim3(Tq / 64, D / 64), 256, 0, stream>>>(yb, w_proj, out);
}

// Round 2
// 737.110 us; speedup vs baseline: 3.9739x; 3.9739x over previous
//
#include <hip/hip_runtime.h>
#include <hip/hip_bf16.h>
#include <math.h>

// Problem constants
constexpr int Tq  = 4096;   // sequence length
constexpr int D   = 1024;   // model dim
constexpr int H   = 16;     // query heads
constexpr int HKV = 4;      // kv heads
constexpr int HD  = 64;     // head dim
constexpr int KVD = HKV * HD;        // 256
constexpr int NQKV = D + 2 * KVD;    // 1536

typedef __attribute__((ext_vector_type(8))) short bf16x8;
typedef __attribute__((ext_vector_type(4))) float f32x4;

static __device__ inline unsigned short f2bf(float f) {
    __hip_bfloat16 h = __float2bfloat16(f);
    return *reinterpret_cast<unsigned short*>(&h);
}

// ---------------------------------------------------------------------------
// GEMM: qkv = x @ w_qkv^T   (f32, 64x64 tile, BK=16, 256 thr, 4x4/thr)
// Q,K written f32 [h][t][d] (norm_rope will bf16 them); V written bf16
// TRANSPOSED [hkv][d][t] so attention's PV B-operand stages directly.
// ---------------------------------------------------------------------------
__global__ __launch_bounds__(256)
void gemm_qkv(const float* __restrict__ A, const float* __restrict__ B,
              float* __restrict__ qb, float* __restrict__ kb,
              unsigned short* __restrict__ vbf)
{
    __shared__ float As[16][65];
    __shared__ float Bs[16][65];
    const int K = D;
    const int tid = threadIdx.x;
    const int ty = tid >> 4, tx = tid & 15;
    const int m0 = blockIdx.x * 64;
    const int n0 = blockIdx.y * 64;

    float acc[4][4] = {};

    for (int k0 = 0; k0 < K; k0 += 16) {
        {
            const int m = tid >> 2, kq = (tid & 3) * 4;
            float4 av = *(const float4*)(A + (size_t)(m0 + m) * K + k0 + kq);
            As[kq + 0][m] = av.x; As[kq + 1][m] = av.y;
            As[kq + 2][m] = av.z; As[kq + 3][m] = av.w;
            float4 bv = *(const float4*)(B + (size_t)(n0 + m) * K + k0 + kq);
            Bs[kq + 0][m] = bv.x; Bs[kq + 1][m] = bv.y;
            Bs[kq + 2][m] = bv.z; Bs[kq + 3][m] = bv.w;
        }
        __syncthreads();
        #pragma unroll
        for (int kk = 0; kk < 16; ++kk) {
            float a[4], b[4];
            #pragma unroll
            for (int i = 0; i < 4; ++i) a[i] = As[kk][ty * 4 + i];
            #pragma unroll
            for (int j = 0; j < 4; ++j) b[j] = Bs[kk][tx * 4 + j];
            #pragma unroll
            for (int i = 0; i < 4; ++i)
                #pragma unroll
                for (int j = 0; j < 4; ++j)
                    acc[i][j] += a[i] * b[j];
        }
        __syncthreads();
    }

    #pragma unroll
    for (int i = 0; i < 4; ++i) {
        const int t = m0 + ty * 4 + i;
        #pragma unroll
        for (int j = 0; j < 4; ++j) {
            const int jj = n0 + tx * 4 + j;
            const int d = jj & 63;
            const float v = acc[i][j];
            if (jj < D) {
                qb[((size_t)(jj >> 6) * Tq + t) * HD + d] = v;
            } else if (jj < D + KVD) {
                kb[((size_t)((jj - D) >> 6) * Tq + t) * HD + d] = v;
            } else {
                const int hh = (jj - D - KVD) >> 6;
                vbf[((size_t)hh * HD + d) * Tq + t] = f2bf(v);
            }
        }
    }
}

// ---------------------------------------------------------------------------
// Output projection: out = y @ w_proj^T  (f32)
// ---------------------------------------------------------------------------
__global__ __launch_bounds__(256)
void gemm_proj(const float* __restrict__ A, const float* __restrict__ B,
               float* __restrict__ C)
{
    __shared__ float As[16][65];
    __shared__ float Bs[16][65];
    const int K = D;
    const int tid = threadIdx.x;
    const int ty = tid >> 4, tx = tid & 15;
    const int m0 = blockIdx.x * 64;
    const int n0 = blockIdx.y * 64;

    float acc[4][4] = {};

    for (int k0 = 0; k0 < K; k0 += 16) {
        {
            const int m = tid >> 2, kq = (tid & 3) * 4;
            float4 av = *(const float4*)(A + (size_t)(m0 + m) * K + k0 + kq);
            As[kq + 0][m] = av.x; As[kq + 1][m] = av.y;
            As[kq + 2][m] = av.z; As[kq + 3][m] = av.w;
            float4 bv = *(const float4*)(B + (size_t)(n0 + m) * K + k0 + kq);
            Bs[kq + 0][m] = bv.x; Bs[kq + 1][m] = bv.y;
            Bs[kq + 2][m] = bv.z; Bs[kq + 3][m] = bv.w;
        }
        __syncthreads();
        #pragma unroll
        for (int kk = 0; kk < 16; ++kk) {
            float a[4], b[4];
            #pragma unroll
            for (int i = 0; i < 4; ++i) a[i] = As[kk][ty * 4 + i];
            #pragma unroll
            for (int j = 0; j < 4; ++j) b[j] = Bs[kk][tx * 4 + j];
            #pragma unroll
            for (int i = 0; i < 4; ++i)
                #pragma unroll
                for (int j = 0; j < 4; ++j)
                    acc[i][j] += a[i] * b[j];
        }
        __syncthreads();
    }

    #pragma unroll
    for (int i = 0; i < 4; ++i) {
        const int t = m0 + ty * 4 + i;
        #pragma unroll
        for (int j = 0; j < 4; ++j) {
            C[(size_t)t * D + n0 + tx * 4 + j] = acc[i][j];
        }
    }
}

// ---------------------------------------------------------------------------
// Per-row (t, head) RMS norm + rotary + gain. One 64-lane wave per row.
// Reads f32 q/k, writes bf16 q/k for the MFMA attention.
// ---------------------------------------------------------------------------
__global__ __launch_bounds__(256)
void norm_rope(const float* __restrict__ qb, const float* __restrict__ kb,
               unsigned short* __restrict__ qbf, unsigned short* __restrict__ kbf,
               const float* __restrict__ gain)
{
    const int tid  = threadIdx.x;
    const int lane = tid & 63;
    const long row = (long)blockIdx.x * 4 + (tid >> 6);
    const long QROWS = (long)H * Tq;

    const float* base;
    unsigned short* dst;
    int t;
    float g;
    if (row < QROWS) {
        base = qb + row * HD;
        dst = qbf + row * HD;
        t = (int)(row & (Tq - 1));
        g = gain[row >> 12];           // h = row / Tq (Tq = 2^12)
    } else {
        const long r2 = row - QROWS;
        base = kb + r2 * HD;
        dst = kbf + r2 * HD;
        t = (int)(r2 & (Tq - 1));
        g = 1.0f;
    }

    float v = base[lane];
    float ss = v * v;
    #pragma unroll
    for (int m = 1; m < 64; m <<= 1) ss += __shfl_xor(ss, m);
    const float rms = rsqrtf(ss * (1.0f / 64.0f) + 1.1920929e-07f);
    const float vn = v * rms;
    const float p = __shfl_xor(vn, 32);

    const int i = lane & 31;
    const float invf = __expf((float)i * -0.28782313662425572f);
    const float ang = (float)t * invf;
    float s, c;
    sincosf(ang, &s, &c);
    const float res = vn * c + ((lane < 32) ? p * s : -(p * s));
    dst[lane] = f2bf(res * g);
}

// ---------------------------------------------------------------------------
// Flash attention, bf16 MFMA (16x16x32). Block = (head, 128 q rows),
// 4 waves x 32 q rows. K tile [64 keys][64 d], V tile transposed [64 d][64 t],
// both padded to 72 bf16/row (2-way conflicts only). P round-trips through a
// per-wave LDS buffer (C-layout -> A-layout, per m120).
// ---------------------------------------------------------------------------
__global__ __launch_bounds__(256)
void attn_mfma(const unsigned short* __restrict__ qbf,
               const unsigned short* __restrict__ kbf,
               const unsigned short* __restrict__ vbf,
               float* __restrict__ yb, const int nqt)
{
    __shared__ __align__(16) unsigned short Ks[64 * 72];
    __shared__ __align__(16) unsigned short Vs[64 * 72];
    __shared__ __align__(16) unsigned short Ps[4][32 * 72];

    const int qt   = nqt - 1 - blockIdx.x;   // long blocks first
    const int h    = blockIdx.y;
    const int hkv  = h >> 2;
    const int tid  = threadIdx.x;
    const int lane = tid & 63;
    const int w    = tid >> 6;
    const int l15  = lane & 15;
    const int quad = lane >> 4;

    // Q fragments: A[m=l15][k=quad*8+j], 2 m-tiles x 2 k-steps
    bf16x8 qfrag[2][2];
    const size_t qbase = ((size_t)h * Tq + (size_t)qt * 128 + w * 32) * HD;
    #pragma unroll
    for (int mt = 0; mt < 2; ++mt)
        #pragma unroll
        for (int ks = 0; ks < 2; ++ks)
            qfrag[mt][ks] = *(const bf16x8*)(qbf + qbase +
                (size_t)(mt * 16 + l15) * HD + ks * 32 + quad * 8);

    f32x4 o[2][4];
    float m_i[2][4], l_i[2][4];
    #pragma unroll
    for (int mt = 0; mt < 2; ++mt)
        #pragma unroll
        for (int r = 0; r < 4; ++r) {
            m_i[mt][r] = -INFINITY; l_i[mt][r] = 0.f;
            o[mt][r] = (f32x4){0.f, 0.f, 0.f, 0.f};
        }

    const int q0        = qt * 128 + w * 32;
    const int ktmax_blk = 2 * qt + 1;
    const int ktmax_w   = (q0 + 31) >> 6;

    for (int kt = 0; kt <= ktmax_blk; ++kt) {
        __syncthreads();   // previous tile's fragment reads complete
        {
            const int kbt = kt * 64;
            #pragma unroll
            for (int it = 0; it < 2; ++it) {
                const int cid = tid + it * 256;
                const int row = cid >> 3, col = cid & 7;
                *(float4*)&Ks[row * 72 + col * 8] =
                    *(const float4*)(kbf + ((size_t)hkv * Tq + kbt + row) * HD + col * 8);
                *(float4*)&Vs[row * 72 + col * 8] =
                    *(const float4*)(vbf + ((size_t)hkv * HD + row) * Tq + kbt + col * 8);
            }
        }
        __syncthreads();
        if (kt > ktmax_w) continue;   // fully masked for this wave

        // S = Q K^T : D[m=q][n=kcol]
        f32x4 sacc[2][4];
        #pragma unroll
        for (int mt = 0; mt < 2; ++mt)
            #pragma unroll
            for (int nb = 0; nb < 4; ++nb)
                sacc[mt][nb] = (f32x4){0.f, 0.f, 0.f, 0.f};
        #pragma unroll
        for (int ks = 0; ks < 2; ++ks) {
            #pragma unroll
            for (int nb = 0; nb < 4; ++nb) {
                bf16x8 kf = *(const bf16x8*)&Ks[(l15 + 16 * nb) * 72 + quad * 8 + ks * 32];
                sacc[0][nb] = __builtin_amdgcn_mfma_f32_16x16x32_bf16(
                    qfrag[0][ks], kf, sacc[0][nb], 0, 0, 0);
                sacc[1][nb] = __builtin_amdgcn_mfma_f32_16x16x32_bf16(
                    qfrag[1][ks], kf, sacc[1][nb], 0, 0, 0);
            }
        }

        const bool diag = (kt * 64 + 63 > q0);
        #pragma unroll
        for (int mt = 0; mt < 2; ++mt) {
            #pragma unroll
            for (int r = 0; r < 4; ++r) {
                const int qg = q0 + mt * 16 + quad * 4 + r;
                float sv[4];
                float mx = -3.0e38f;
                #pragma unroll
                for (int nb = 0; nb < 4; ++nb) {
                    float s = sacc[mt][nb][r] * 0.125f;
                    if (diag && (kt * 64 + nb * 16 + l15 > qg)) s = -3.0e38f;
                    sv[nb] = s;
                    mx = fmaxf(mx, s);
                }
                mx = fmaxf(mx, __shfl_xor(mx, 1));
                mx = fmaxf(mx, __shfl_xor(mx, 2));
                mx = fmaxf(mx, __shfl_xor(mx, 4));
                mx = fmaxf(mx, __shfl_xor(mx, 8));
                const float mn = fmaxf(m_i[mt][r], mx);
                const float al = __expf(m_i[mt][r] - mn);
                m_i[mt][r] = mn;
                float psum = 0.f;
                #pragma unroll
                for (int nb = 0; nb < 4; ++nb) {
                    const float p = __expf(sv[nb] - mn);
                    psum += p;
                    Ps[w][(mt * 16 + quad * 4 + r) * 72 + l15 + 16 * nb] = f2bf(p);
                }
                l_i[mt][r] = l_i[mt][r] * al + psum;
                #pragma unroll
                for (int nb = 0; nb < 4; ++nb) o[mt][nb][r] *= al;
            }
        }

        // O += P V : A[m=q][k=kcol] from Ps, B[k=kcol][n=d] from Vs rows
        #pragma unroll
        for (int ks = 0; ks < 2; ++ks) {
            bf16x8 pf0 = *(const bf16x8*)&Ps[w][(l15) * 72 + quad * 8 + ks * 32];
            bf16x8 pf1 = *(const bf16x8*)&Ps[w][(16 + l15) * 72 + quad * 8 + ks * 32];
            #pragma unroll
            for (int nb = 0; nb < 4; ++nb) {
                bf16x8 vf = *(const bf16x8*)&Vs[(l15 + 16 * nb) * 72 + quad * 8 + ks * 32];
                o[0][nb] = __builtin_amdgcn_mfma_f32_16x16x32_bf16(pf0, vf, o[0][nb], 0, 0, 0);
                o[1][nb] = __builtin_amdgcn_mfma_f32_16x16x32_bf16(pf1, vf, o[1][nb], 0, 0, 0);
            }
        }
    }

    // final l reduction over the 16-lane row groups, then write y [t][h*64+d]
    #pragma unroll
    for (int mt = 0; mt < 2; ++mt) {
        #pragma unroll
        for (int r = 0; r < 4; ++r) {
            float l = l_i[mt][r];
            l += __shfl_xor(l, 1);
            l += __shfl_xor(l, 2);
            l += __shfl_xor(l, 4);
            l += __shfl_xor(l, 8);
            const float inv = 1.0f / l;
            const int qg = q0 + mt * 16 + quad * 4 + r;
            #pragma unroll
            for (int nb = 0; nb < 4; ++nb) {
                yb[(size_t)qg * D + h * HD + nb * 16 + l15] = o[mt][nb][r] * inv;
            }
        }
    }
}

// ---------------------------------------------------------------------------
extern "C" void kernel_launch(void* const* d_in, const int* in_sizes, int n_in,
                              void* d_out, int out_size, void* d_ws, size_t ws_size,
                              hipStream_t stream)
{
    const float* x      = (const float*)d_in[0];   // [1, 4096, 1024]
    const float* w_qkv  = (const float*)d_in[1];   // [1536, 1024]
    const float* w_proj = (const float*)d_in[2];   // [1024, 1024]
    const float* q_gain = (const float*)d_in[3];   // [16]
    float* out = (float*)d_out;                    // [4096, 1024]

    // workspace layout
    float* qb  = (float*)d_ws;                         // 4M f32
    float* kb  = qb + (size_t)H * Tq * HD;             // 1M f32
    float* yb  = kb + (size_t)HKV * Tq * HD;           // 4M f32
    unsigned short* qbf = (unsigned short*)(yb + (size_t)Tq * D);  // 4M bf16
    unsigned short* kbf = qbf + (size_t)H * Tq * HD;               // 1M bf16
    unsigned short* vbf = kbf + (size_t)HKV * Tq * HD;             // 1M bf16

    gemm_qkv<<<dim3(Tq / 64, NQKV / 64), 256, 0, stream>>>(x, w_qkv, qb, kb, vbf);
    norm_rope<<<dim3((H + HKV) * Tq / 4), 256, 0, stream>>>(qb, kb, qbf, kbf, q_gain);
    attn_mfma<<<dim3(Tq / 128, H), 256, 0, stream>>>(qbf, kbf, vbf, yb, Tq / 128);
    gemm_proj<<<dim3(Tq / 64, D / 64), 256, 0, stream>>>(yb, w_proj, out);
}

// Round 3
// 379.729 us; speedup vs baseline: 7.7139x; 1.9411x over previous
//
#include <hip/hip_runtime.h>
#include <hip/hip_bf16.h>
#include <math.h>

// Problem constants
constexpr int Tq  = 4096;   // sequence length
constexpr int D   = 1024;   // model dim
constexpr int H   = 16;     // query heads
constexpr int HKV = 4;      // kv heads
constexpr int HD  = 64;     // head dim
constexpr int NQKV = D + 2 * HKV * HD;   // 1536

typedef __attribute__((ext_vector_type(8))) short bf16x8;
typedef __attribute__((ext_vector_type(4))) float f32x4;

static __device__ inline unsigned short f2bf(float f) {
    __hip_bfloat16 h = __float2bfloat16(f);
    return *reinterpret_cast<unsigned short*>(&h);
}
static __device__ inline float bf2f(unsigned short u) {
    unsigned int x = ((unsigned int)u) << 16;
    return __uint_as_float(x);
}

#define GLOBAL_LOAD_LDS16(g, l)                                                   \
    __builtin_amdgcn_global_load_lds(                                             \
        (const __attribute__((address_space(1))) void*)(g),                       \
        (__attribute__((address_space(3))) void*)(l), 16, 0, 0)

// ---------------------------------------------------------------------------
// f32 -> bf16 elementwise convert (n multiple of 4)
// ---------------------------------------------------------------------------
__global__ __launch_bounds__(256)
void to_bf16(const float* __restrict__ s, unsigned short* __restrict__ d, int n)
{
    const int i = (blockIdx.x * 256 + threadIdx.x) * 4;
    if (i >= n) return;
    float4 v = *(const float4*)(s + i);
    ushort4 o;
    o.x = f2bf(v.x); o.y = f2bf(v.y); o.z = f2bf(v.z); o.w = f2bf(v.w);
    *(ushort4*)(d + i) = o;
}

// ---------------------------------------------------------------------------
// bf16 MFMA GEMM mainloop (m97 structure): C[M,N] = A[M,K] @ B[N,K]^T
// 128x128 tile, BK=32, 4 waves each 64x64. LDS unpadded (global_load_lds
// writes base + lane*16); chunk slot XOR-swizzled by row bits so fragment
// ds_read_b128 is 2-way-conflict-free.
// ---------------------------------------------------------------------------
#define GEMM_MAINLOOP(Aptr, Bptr, Kdim)                                           \
    __shared__ __align__(16) unsigned short As[128 * 32];                         \
    __shared__ __align__(16) unsigned short Bs[128 * 32];                         \
    const int tid  = threadIdx.x;                                                 \
    const int lane = tid & 63;                                                    \
    const int w    = tid >> 6;                                                    \
    const int l15  = lane & 15, quad = lane >> 4;                                 \
    const int wm   = w >> 1, wn = w & 1;                                          \
    const int m0   = blockIdx.x * 128, n0 = blockIdx.y * 128;                     \
    const int srow   = lane >> 2;                                                 \
    const int schunk = (lane & 3) ^ ((lane >> 3) & 3);                            \
    const int fs     = (quad ^ ((l15 >> 1) & 3)) * 8;                             \
    f32x4 acc[4][4];                                                              \
    _Pragma("unroll")                                                             \
    for (int i = 0; i < 4; ++i)                                                   \
        _Pragma("unroll")                                                         \
        for (int j = 0; j < 4; ++j) acc[i][j] = (f32x4){0.f, 0.f, 0.f, 0.f};      \
    for (int k0 = 0; k0 < (Kdim); k0 += 32) {                                     \
        __syncthreads();                                                          \
        _Pragma("unroll")                                                         \
        for (int it = 0; it < 2; ++it) {                                          \
            const int r = w * 32 + it * 16 + srow;                                \
            GLOBAL_LOAD_LDS16((Aptr) + (size_t)(m0 + r) * (Kdim) + k0 + schunk * 8,\
                              &As[(w * 32 + it * 16) * 32]);                      \
            GLOBAL_LOAD_LDS16((Bptr) + (size_t)(n0 + r) * (Kdim) + k0 + schunk * 8,\
                              &Bs[(w * 32 + it * 16) * 32]);                      \
        }                                                                         \
        __syncthreads();                                                          \
        bf16x8 af[4], bfr[4];                                                     \
        _Pragma("unroll")                                                         \
        for (int i = 0; i < 4; ++i) {                                             \
            af[i]  = *(const bf16x8*)&As[(wm * 64 + i * 16 + l15) * 32 + fs];     \
            bfr[i] = *(const bf16x8*)&Bs[(wn * 64 + i * 16 + l15) * 32 + fs];     \
        }                                                                         \
        _Pragma("unroll")                                                         \
        for (int i = 0; i < 4; ++i)                                               \
            _Pragma("unroll")                                                     \
            for (int j = 0; j < 4; ++j)                                           \
                acc[i][j] = __builtin_amdgcn_mfma_f32_16x16x32_bf16(              \
                    af[i], bfr[j], acc[i][j], 0, 0, 0);                           \
    }

// qkv = x @ w_qkv^T; Q,K bf16 [h][t][d] (pre-norm), V bf16 transposed [hkv][d][t]
__global__ __launch_bounds__(256)
void gemm_qkv_mfma(const unsigned short* __restrict__ A,
                   const unsigned short* __restrict__ B,
                   unsigned short* __restrict__ qbf,
                   unsigned short* __restrict__ kbf,
                   unsigned short* __restrict__ vbf)
{
    GEMM_MAINLOOP(A, B, 1024)
    #pragma unroll
    for (int i = 0; i < 4; ++i) {
        #pragma unroll
        for (int j = 0; j < 4; ++j) {
            const int n = n0 + wn * 64 + j * 16 + l15;
            #pragma unroll
            for (int r = 0; r < 4; ++r) {
                const int t = m0 + wm * 64 + i * 16 + quad * 4 + r;
                const unsigned short v = f2bf(acc[i][j][r]);
                if (n < D) {
                    qbf[((size_t)(n >> 6) * Tq + t) * HD + (n & 63)] = v;
                } else if (n < D + 256) {
                    kbf[((size_t)((n - D) >> 6) * Tq + t) * HD + (n & 63)] = v;
                } else {
                    vbf[((size_t)((n - D - 256) >> 6) * HD + (n & 63)) * Tq + t] = v;
                }
            }
        }
    }
}

// out = y @ w_proj^T  (f32 output)
__global__ __launch_bounds__(256)
void gemm_proj_mfma(const unsigned short* __restrict__ A,
                    const unsigned short* __restrict__ B,
                    float* __restrict__ C)
{
    GEMM_MAINLOOP(A, B, 1024)
    #pragma unroll
    for (int i = 0; i < 4; ++i) {
        #pragma unroll
        for (int j = 0; j < 4; ++j) {
            const int n = n0 + wn * 64 + j * 16 + l15;
            #pragma unroll
            for (int r = 0; r < 4; ++r) {
                const int t = m0 + wm * 64 + i * 16 + quad * 4 + r;
                C[(size_t)t * D + n] = acc[i][j][r];
            }
        }
    }
}

// ---------------------------------------------------------------------------
// Per-row (t, head) RMS norm + rotary + gain, bf16 in/out in place.
// ---------------------------------------------------------------------------
__global__ __launch_bounds__(256)
void norm_rope(unsigned short* __restrict__ qbf, unsigned short* __restrict__ kbf,
               const float* __restrict__ gain)
{
    const int tid  = threadIdx.x;
    const int lane = tid & 63;
    const long row = (long)blockIdx.x * 4 + (tid >> 6);
    const long QROWS = (long)H * Tq;

    unsigned short* base;
    int t;
    float g;
    if (row < QROWS) {
        base = qbf + row * HD;
        t = (int)(row & (Tq - 1));
        g = gain[row >> 12];           // h = row / Tq (Tq = 2^12)
    } else {
        const long r2 = row - QROWS;
        base = kbf + r2 * HD;
        t = (int)(r2 & (Tq - 1));
        g = 1.0f;
    }

    float v = bf2f(base[lane]);
    float ss = v * v;
    #pragma unroll
    for (int m = 1; m < 64; m <<= 1) ss += __shfl_xor(ss, m);
    const float rms = rsqrtf(ss * (1.0f / 64.0f) + 1.1920929e-07f);
    const float vn = v * rms;
    const float p = __shfl_xor(vn, 32);

    const int i = lane & 31;
    const float invf = __expf((float)i * -0.28782313662425572f);
    const float ang = (float)t * invf;
    float s, c;
    sincosf(ang, &s, &c);
    const float res = vn * c + ((lane < 32) ? p * s : -(p * s));
    base[lane] = f2bf(res * g);
}

// ---------------------------------------------------------------------------
// Flash attention, bf16 MFMA (16x16x32). Block = (head, 128 q rows),
// 4 waves x 32 q rows. Writes bf16 y [t][h*64+d] for the proj GEMM.
// ---------------------------------------------------------------------------
__global__ __launch_bounds__(256)
void attn_mfma(const unsigned short* __restrict__ qbf,
               const unsigned short* __restrict__ kbf,
               const unsigned short* __restrict__ vbf,
               unsigned short* __restrict__ ybf, const int nqt)
{
    __shared__ __align__(16) unsigned short Ks[64 * 72];
    __shared__ __align__(16) unsigned short Vs[64 * 72];
    __shared__ __align__(16) unsigned short Ps[4][32 * 72];

    const int qt   = nqt - 1 - blockIdx.x;   // long blocks first
    const int h    = blockIdx.y;
    const int hkv  = h >> 2;
    const int tid  = threadIdx.x;
    const int lane = tid & 63;
    const int w    = tid >> 6;
    const int l15  = lane & 15;
    const int quad = lane >> 4;

    bf16x8 qfrag[2][2];
    const size_t qbase = ((size_t)h * Tq + (size_t)qt * 128 + w * 32) * HD;
    #pragma unroll
    for (int mt = 0; mt < 2; ++mt)
        #pragma unroll
        for (int ks = 0; ks < 2; ++ks)
            qfrag[mt][ks] = *(const bf16x8*)(qbf + qbase +
                (size_t)(mt * 16 + l15) * HD + ks * 32 + quad * 8);

    f32x4 o[2][4];
    float m_i[2][4], l_i[2][4];
    #pragma unroll
    for (int mt = 0; mt < 2; ++mt)
        #pragma unroll
        for (int r = 0; r < 4; ++r) {
            m_i[mt][r] = -INFINITY; l_i[mt][r] = 0.f;
            o[mt][r] = (f32x4){0.f, 0.f, 0.f, 0.f};
        }

    const int q0        = qt * 128 + w * 32;
    const int ktmax_blk = 2 * qt + 1;
    const int ktmax_w   = (q0 + 31) >> 6;

    for (int kt = 0; kt <= ktmax_blk; ++kt) {
        __syncthreads();
        {
            const int kbt = kt * 64;
            #pragma unroll
            for (int it = 0; it < 2; ++it) {
                const int cid = tid + it * 256;
                const int row = cid >> 3, col = cid & 7;
                *(float4*)&Ks[row * 72 + col * 8] =
                    *(const float4*)(kbf + ((size_t)hkv * Tq + kbt + row) * HD + col * 8);
                *(float4*)&Vs[row * 72 + col * 8] =
                    *(const float4*)(vbf + ((size_t)hkv * HD + row) * Tq + kbt + col * 8);
            }
        }
        __syncthreads();
        if (kt > ktmax_w) continue;   // fully masked for this wave

        f32x4 sacc[2][4];
        #pragma unroll
        for (int mt = 0; mt < 2; ++mt)
            #pragma unroll
            for (int nb = 0; nb < 4; ++nb)
                sacc[mt][nb] = (f32x4){0.f, 0.f, 0.f, 0.f};
        #pragma unroll
        for (int ks = 0; ks < 2; ++ks) {
            #pragma unroll
            for (int nb = 0; nb < 4; ++nb) {
                bf16x8 kf = *(const bf16x8*)&Ks[(l15 + 16 * nb) * 72 + quad * 8 + ks * 32];
                sacc[0][nb] = __builtin_amdgcn_mfma_f32_16x16x32_bf16(
                    qfrag[0][ks], kf, sacc[0][nb], 0, 0, 0);
                sacc[1][nb] = __builtin_amdgcn_mfma_f32_16x16x32_bf16(
                    qfrag[1][ks], kf, sacc[1][nb], 0, 0, 0);
            }
        }

        const bool diag = (kt * 64 + 63 > q0);
        #pragma unroll
        for (int mt = 0; mt < 2; ++mt) {
            #pragma unroll
            for (int r = 0; r < 4; ++r) {
                const int qg = q0 + mt * 16 + quad * 4 + r;
                float sv[4];
                float mx = -3.0e38f;
                #pragma unroll
                for (int nb = 0; nb < 4; ++nb) {
                    float s = sacc[mt][nb][r] * 0.125f;
                    if (diag && (kt * 64 + nb * 16 + l15 > qg)) s = -3.0e38f;
                    sv[nb] = s;
                    mx = fmaxf(mx, s);
                }
                mx = fmaxf(mx, __shfl_xor(mx, 1));
                mx = fmaxf(mx, __shfl_xor(mx, 2));
                mx = fmaxf(mx, __shfl_xor(mx, 4));
                mx = fmaxf(mx, __shfl_xor(mx, 8));
                const float mn = fmaxf(m_i[mt][r], mx);
                const float al = __expf(m_i[mt][r] - mn);
                m_i[mt][r] = mn;
                float psum = 0.f;
                #pragma unroll
                for (int nb = 0; nb < 4; ++nb) {
                    const float p = __expf(sv[nb] - mn);
                    psum += p;
                    Ps[w][(mt * 16 + quad * 4 + r) * 72 + l15 + 16 * nb] = f2bf(p);
                }
                l_i[mt][r] = l_i[mt][r] * al + psum;
                #pragma unroll
                for (int nb = 0; nb < 4; ++nb) o[mt][nb][r] *= al;
            }
        }

        #pragma unroll
        for (int ks = 0; ks < 2; ++ks) {
            bf16x8 pf0 = *(const bf16x8*)&Ps[w][(l15) * 72 + quad * 8 + ks * 32];
            bf16x8 pf1 = *(const bf16x8*)&Ps[w][(16 + l15) * 72 + quad * 8 + ks * 32];
            #pragma unroll
            for (int nb = 0; nb < 4; ++nb) {
                bf16x8 vf = *(const bf16x8*)&Vs[(l15 + 16 * nb) * 72 + quad * 8 + ks * 32];
                o[0][nb] = __builtin_amdgcn_mfma_f32_16x16x32_bf16(pf0, vf, o[0][nb], 0, 0, 0);
                o[1][nb] = __builtin_amdgcn_mfma_f32_16x16x32_bf16(pf1, vf, o[1][nb], 0, 0, 0);
            }
        }
    }

    #pragma unroll
    for (int mt = 0; mt < 2; ++mt) {
        #pragma unroll
        for (int r = 0; r < 4; ++r) {
            float l = l_i[mt][r];
            l += __shfl_xor(l, 1);
            l += __shfl_xor(l, 2);
            l += __shfl_xor(l, 4);
            l += __shfl_xor(l, 8);
            const float inv = 1.0f / l;
            const int qg = q0 + mt * 16 + quad * 4 + r;
            #pragma unroll
            for (int nb = 0; nb < 4; ++nb) {
                ybf[(size_t)qg * D + h * HD + nb * 16 + l15] = f2bf(o[mt][nb][r] * inv);
            }
        }
    }
}

// ---------------------------------------------------------------------------
extern "C" void kernel_launch(void* const* d_in, const int* in_sizes, int n_in,
                              void* d_out, int out_size, void* d_ws, size_t ws_size,
                              hipStream_t stream)
{
    const float* x      = (const float*)d_in[0];   // [1, 4096, 1024]
    const float* w_qkv  = (const float*)d_in[1];   // [1536, 1024]
    const float* w_proj = (const float*)d_in[2];   // [1024, 1024]
    const float* q_gain = (const float*)d_in[3];   // [16]
    float* out = (float*)d_out;                    // [4096, 1024]

    // workspace layout (bf16, 33 MB total)
    unsigned short* qbf = (unsigned short*)d_ws;              // 4M
    unsigned short* kbf = qbf + (size_t)H * Tq * HD;          // 1M
    unsigned short* vbf = kbf + (size_t)HKV * Tq * HD;        // 1M
    unsigned short* ybf = vbf + (size_t)HKV * Tq * HD;        // 4M
    unsigned short* xbf = ybf + (size_t)Tq * D;               // 4M
    unsigned short* wqkvbf  = xbf + (size_t)Tq * D;           // 1.5M
    unsigned short* wprojbf = wqkvbf + (size_t)NQKV * D;      // 1M

    to_bf16<<<dim3(Tq * D / 1024), 256, 0, stream>>>(x, xbf, Tq * D);
    to_bf16<<<dim3(NQKV * D / 1024), 256, 0, stream>>>(w_qkv, wqkvbf, NQKV * D);
    to_bf16<<<dim3(D * D / 1024), 256, 0, stream>>>(w_proj, wprojbf, D * D);

    gemm_qkv_mfma<<<dim3(Tq / 128, NQKV / 128), 256, 0, stream>>>(xbf, wqkvbf, qbf, kbf, vbf);
    norm_rope<<<dim3((H + HKV) * Tq / 4), 256, 0, stream>>>(qbf, kbf, q_gain);
    attn_mfma<<<dim3(Tq / 128, H), 256, 0, stream>>>(qbf, kbf, vbf, ybf, Tq / 128);
    gemm_proj_mfma<<<dim3(Tq / 128, D / 128), 256, 0, stream>>>(ybf, wprojbf, out);
}

// Round 5
// 276.886 us; speedup vs baseline: 10.5791x; 1.3714x over previous
//
#include <hip/hip_runtime.h>
#include <hip/hip_bf16.h>
#include <math.h>

// Problem constants
constexpr int Tq  = 4096;   // sequence length
constexpr int D   = 1024;   // model dim
constexpr int H   = 16;     // query heads
constexpr int HKV = 4;      // kv heads
constexpr int HD  = 64;     // head dim
constexpr int NQKV = D + 2 * HKV * HD;   // 1536

typedef __attribute__((ext_vector_type(8))) short bf16x8;
typedef __attribute__((ext_vector_type(4))) float f32x4;

static __device__ inline unsigned short f2bf(float f) {
    __hip_bfloat16 h = __float2bfloat16(f);
    return *reinterpret_cast<unsigned short*>(&h);
}
static __device__ inline float bf2f(unsigned short u) {
    unsigned int x = ((unsigned int)u) << 16;
    return __uint_as_float(x);
}

#define GLOBAL_LOAD_LDS16(g, l)                                                   \
    __builtin_amdgcn_global_load_lds(                                             \
        (const __attribute__((address_space(1))) void*)(g),                       \
        (__attribute__((address_space(3))) void*)(l), 16, 0, 0)

// ---------------------------------------------------------------------------
// f32 -> bf16 elementwise convert (n multiple of 4)
// ---------------------------------------------------------------------------
__global__ __launch_bounds__(256)
void to_bf16(const float* __restrict__ s, unsigned short* __restrict__ d, int n)
{
    const int i = (blockIdx.x * 256 + threadIdx.x) * 4;
    if (i >= n) return;
    float4 v = *(const float4*)(s + i);
    ushort4 o;
    o.x = f2bf(v.x); o.y = f2bf(v.y); o.z = f2bf(v.z); o.w = f2bf(v.w);
    *(ushort4*)(d + i) = o;
}

// ---------------------------------------------------------------------------
// bf16 MFMA GEMM mainloop (m97 structure): C[M,N] = A[M,K] @ B[N,K]^T
// 128x128 tile, BK=32, 4 waves each 64x64.  (unchanged from round 3 - passed)
// ---------------------------------------------------------------------------
#define GEMM_MAINLOOP(Aptr, Bptr, Kdim)                                           \
    __shared__ __align__(16) unsigned short As[128 * 32];                         \
    __shared__ __align__(16) unsigned short Bs[128 * 32];                         \
    const int tid  = threadIdx.x;                                                 \
    const int lane = tid & 63;                                                    \
    const int w    = tid >> 6;                                                    \
    const int l15  = lane & 15, quad = lane >> 4;                                 \
    const int wm   = w >> 1, wn = w & 1;                                          \
    const int m0   = blockIdx.x * 128, n0 = blockIdx.y * 128;                     \
    const int srow   = lane >> 2;                                                 \
    const int schunk = (lane & 3) ^ ((lane >> 3) & 3);                            \
    const int fs     = (quad ^ ((l15 >> 1) & 3)) * 8;                             \
    f32x4 acc[4][4];                                                              \
    _Pragma("unroll")                                                             \
    for (int i = 0; i < 4; ++i)                                                   \
        _Pragma("unroll")                                                         \
        for (int j = 0; j < 4; ++j) acc[i][j] = (f32x4){0.f, 0.f, 0.f, 0.f};      \
    for (int k0 = 0; k0 < (Kdim); k0 += 32) {                                     \
        __syncthreads();                                                          \
        _Pragma("unroll")                                                         \
        for (int it = 0; it < 2; ++it) {                                          \
            const int r = w * 32 + it * 16 + srow;                                \
            GLOBAL_LOAD_LDS16((Aptr) + (size_t)(m0 + r) * (Kdim) + k0 + schunk * 8,\
                              &As[(w * 32 + it * 16) * 32]);                      \
            GLOBAL_LOAD_LDS16((Bptr) + (size_t)(n0 + r) * (Kdim) + k0 + schunk * 8,\
                              &Bs[(w * 32 + it * 16) * 32]);                      \
        }                                                                         \
        __syncthreads();                                                          \
        bf16x8 af[4], bfr[4];                                                     \
        _Pragma("unroll")                                                         \
        for (int i = 0; i < 4; ++i) {                                             \
            af[i]  = *(const bf16x8*)&As[(wm * 64 + i * 16 + l15) * 32 + fs];     \
            bfr[i] = *(const bf16x8*)&Bs[(wn * 64 + i * 16 + l15) * 32 + fs];     \
        }                                                                         \
        _Pragma("unroll")                                                         \
        for (int i = 0; i < 4; ++i)                                               \
            _Pragma("unroll")                                                     \
            for (int j = 0; j < 4; ++j)                                           \
                acc[i][j] = __builtin_amdgcn_mfma_f32_16x16x32_bf16(              \
                    af[i], bfr[j], acc[i][j], 0, 0, 0);                           \
    }

// qkv = x @ w_qkv^T; Q,K bf16 [h][t][d] (pre-norm), V bf16 transposed [hkv][d][t]
__global__ __launch_bounds__(256)
void gemm_qkv_mfma(const unsigned short* __restrict__ A,
                   const unsigned short* __restrict__ B,
                   unsigned short* __restrict__ qbf,
                   unsigned short* __restrict__ kbf,
                   unsigned short* __restrict__ vbf)
{
    GEMM_MAINLOOP(A, B, 1024)
    #pragma unroll
    for (int i = 0; i < 4; ++i) {
        #pragma unroll
        for (int j = 0; j < 4; ++j) {
            const int n = n0 + wn * 64 + j * 16 + l15;
            #pragma unroll
            for (int r = 0; r < 4; ++r) {
                const int t = m0 + wm * 64 + i * 16 + quad * 4 + r;
                const unsigned short v = f2bf(acc[i][j][r]);
                if (n < D) {
                    qbf[((size_t)(n >> 6) * Tq + t) * HD + (n & 63)] = v;
                } else if (n < D + 256) {
                    kbf[((size_t)((n - D) >> 6) * Tq + t) * HD + (n & 63)] = v;
                } else {
                    vbf[((size_t)((n - D - 256) >> 6) * HD + (n & 63)) * Tq + t] = v;
                }
            }
        }
    }
}

// out = y @ w_proj^T  (f32 output)
__global__ __launch_bounds__(256)
void gemm_proj_mfma(const unsigned short* __restrict__ A,
                    const unsigned short* __restrict__ B,
                    float* __restrict__ C)
{
    GEMM_MAINLOOP(A, B, 1024)
    #pragma unroll
    for (int i = 0; i < 4; ++i) {
        #pragma unroll
        for (int j = 0; j < 4; ++j) {
            const int n = n0 + wn * 64 + j * 16 + l15;
            #pragma unroll
            for (int r = 0; r < 4; ++r) {
                const int t = m0 + wm * 64 + i * 16 + quad * 4 + r;
                C[(size_t)t * D + n] = acc[i][j][r];
            }
        }
    }
}

// ---------------------------------------------------------------------------
// Per-row (t, head) RMS norm + rotary + gain, bf16 in/out in place.
// ---------------------------------------------------------------------------
__global__ __launch_bounds__(256)
void norm_rope(unsigned short* __restrict__ qbf, unsigned short* __restrict__ kbf,
               const float* __restrict__ gain)
{
    const int tid  = threadIdx.x;
    const int lane = tid & 63;
    const long row = (long)blockIdx.x * 4 + (tid >> 6);
    const long QROWS = (long)H * Tq;

    unsigned short* base;
    int t;
    float g;
    if (row < QROWS) {
        base = qbf + row * HD;
        t = (int)(row & (Tq - 1));
        g = gain[row >> 12];
    } else {
        const long r2 = row - QROWS;
        base = kbf + r2 * HD;
        t = (int)(r2 & (Tq - 1));
        g = 1.0f;
    }

    float v = bf2f(base[lane]);
    float ss = v * v;
    #pragma unroll
    for (int m = 1; m < 64; m <<= 1) ss += __shfl_xor(ss, m);
    const float rms = rsqrtf(ss * (1.0f / 64.0f) + 1.1920929e-07f);
    const float vn = v * rms;
    const float p = __shfl_xor(vn, 32);

    const int i = lane & 31;
    const float invf = __expf((float)i * -0.28782313662425572f);
    const float ang = (float)t * invf;
    float s, c;
    sincosf(ang, &s, &c);
    const float res = vn * c + ((lane < 32) ? p * s : -(p * s));
    base[lane] = f2bf(res * g);
}

// ---------------------------------------------------------------------------
// Flash attention, bf16 MFMA, static-max softmax (p = exp(s/8 - 22), exact up
// to rounding: |s| <= 64 since q,k are unit-RMS rows), register-pipelined
// staging into padded LDS (round-3-verified layout, stride 72).
// Block = (head, 64 q rows), 4 waves x 16 q rows. Grid 64x16, long-first.
// ---------------------------------------------------------------------------
__global__ __launch_bounds__(256)
void attn_mfma(const unsigned short* __restrict__ qbf,
               const unsigned short* __restrict__ kbf,
               const unsigned short* __restrict__ vbf,
               unsigned short* __restrict__ ybf)
{
    __shared__ __align__(16) unsigned short Ks[64 * 72];
    __shared__ __align__(16) unsigned short Vs[64 * 72];
    __shared__ __align__(16) unsigned short Ps[4][16 * 72];

    const int qt   = 63 - (int)blockIdx.x;   // long blocks first
    const int h    = blockIdx.y;
    const int hkv  = h >> 2;
    const int tid  = threadIdx.x;
    const int lane = tid & 63;
    const int w    = tid >> 6;
    const int l15  = lane & 15;
    const int quad = lane >> 4;

    // staging geometry: wave w stages rows w*16..w*16+15; each lane 32 B
    const int srow = w * 16 + (lane >> 2);   // K: key row | V: d row
    const int sc   = (lane & 3) * 16;        // column offset in shorts
    const unsigned short* kB = kbf + (size_t)hkv * Tq * HD;
    const unsigned short* vB = vbf + (size_t)hkv * HD * Tq;

    // Q fragments: A[m=l15][k=quad*8+j], one 16-row m-tile, 2 k-steps
    bf16x8 qf[2];
    const size_t qbase = ((size_t)h * Tq + qt * 64 + w * 16) * HD;
    #pragma unroll
    for (int ks = 0; ks < 2; ++ks)
        qf[ks] = *(const bf16x8*)(qbf + qbase + (size_t)l15 * HD + ks * 32 + quad * 8);

    f32x4 o[4];
    float l_i[4];
    #pragma unroll
    for (int r = 0; r < 4; ++r) { o[r] = (f32x4){0.f, 0.f, 0.f, 0.f}; l_i[r] = 0.f; }

    // preload tile 0 into registers
    float4 k0r = *(const float4*)(kB + (size_t)srow * HD + sc);
    float4 k1r = *(const float4*)(kB + (size_t)srow * HD + sc + 8);
    float4 v0r = *(const float4*)(vB + (size_t)srow * Tq + sc);
    float4 v1r = *(const float4*)(vB + (size_t)srow * Tq + sc + 8);

    for (int kt = 0; kt <= qt; ++kt) {
        // stage current tile regs -> LDS (prev iteration's reads done: barrier
        // at end of loop body). The vmcnt wait here is for loads issued a full
        // compute phase ago.
        *(float4*)&Ks[srow * 72 + sc]     = k0r;
        *(float4*)&Ks[srow * 72 + sc + 8] = k1r;
        *(float4*)&Vs[srow * 72 + sc]     = v0r;
        *(float4*)&Vs[srow * 72 + sc + 8] = v1r;

        // issue next tile's global loads; they complete during this compute
        if (kt < qt) {
            const int kbt = (kt + 1) * 64;
            k0r = *(const float4*)(kB + (size_t)(kbt + srow) * HD + sc);
            k1r = *(const float4*)(kB + (size_t)(kbt + srow) * HD + sc + 8);
            v0r = *(const float4*)(vB + (size_t)srow * Tq + kbt + sc);
            v1r = *(const float4*)(vB + (size_t)srow * Tq + kbt + sc + 8);
        }
        __syncthreads();   // tile kt visible to all waves

        // S = Q K^T
        f32x4 sacc[4];
        #pragma unroll
        for (int nb = 0; nb < 4; ++nb) sacc[nb] = (f32x4){0.f, 0.f, 0.f, 0.f};
        #pragma unroll
        for (int ks = 0; ks < 2; ++ks)
            #pragma unroll
            for (int nb = 0; nb < 4; ++nb) {
                bf16x8 kf = *(const bf16x8*)&Ks[(l15 + 16 * nb) * 72 + quad * 8 + ks * 32];
                sacc[nb] = __builtin_amdgcn_mfma_f32_16x16x32_bf16(
                    qf[ks], kf, sacc[nb], 0, 0, 0);
            }

        // static-max softmax: p = exp(s/8 - 22); no running max, no rescale
        if (kt < qt) {   // fully unmasked tile
            #pragma unroll
            for (int r = 0; r < 4; ++r) {
                float ps = 0.f;
                #pragma unroll
                for (int nb = 0; nb < 4; ++nb) {
                    const float p = __expf(fmaf(sacc[nb][r], 0.125f, -22.0f));
                    ps += p;
                    Ps[w][(quad * 4 + r) * 72 + nb * 16 + l15] = f2bf(p);
                }
                l_i[r] += ps;
            }
        } else {         // diagonal tile
            #pragma unroll
            for (int r = 0; r < 4; ++r) {
                const int qg = qt * 64 + w * 16 + quad * 4 + r;
                float ps = 0.f;
                #pragma unroll
                for (int nb = 0; nb < 4; ++nb) {
                    float p = __expf(fmaf(sacc[nb][r], 0.125f, -22.0f));
                    if (kt * 64 + nb * 16 + l15 > qg) p = 0.f;
                    ps += p;
                    Ps[w][(quad * 4 + r) * 72 + nb * 16 + l15] = f2bf(p);
                }
                l_i[r] += ps;
            }
        }

        // O += P V  (per-wave Ps round-trip, round-3-verified)
        #pragma unroll
        for (int ks = 0; ks < 2; ++ks) {
            bf16x8 pf = *(const bf16x8*)&Ps[w][l15 * 72 + quad * 8 + ks * 32];
            #pragma unroll
            for (int nb = 0; nb < 4; ++nb) {
                bf16x8 vf = *(const bf16x8*)&Vs[(l15 + 16 * nb) * 72 + quad * 8 + ks * 32];
                o[nb] = __builtin_amdgcn_mfma_f32_16x16x32_bf16(pf, vf, o[nb], 0, 0, 0);
            }
        }
        __syncthreads();   // all waves done reading Ks/Vs before next staging
    }

    // epilogue: l reduce across the 16 lanes of each quad-row, write bf16 y
    #pragma unroll
    for (int r = 0; r < 4; ++r) {
        float l = l_i[r];
        l += __shfl_xor(l, 1);
        l += __shfl_xor(l, 2);
        l += __shfl_xor(l, 4);
        l += __shfl_xor(l, 8);
        const float inv = 1.0f / l;
        const int qg = qt * 64 + w * 16 + quad * 4 + r;
        #pragma unroll
        for (int nb = 0; nb < 4; ++nb)
            ybf[(size_t)qg * D + h * HD + nb * 16 + l15] = f2bf(o[nb][r] * inv);
    }
}

// ---------------------------------------------------------------------------
extern "C" void kernel_launch(void* const* d_in, const int* in_sizes, int n_in,
                              void* d_out, int out_size, void* d_ws, size_t ws_size,
                              hipStream_t stream)
{
    const float* x      = (const float*)d_in[0];   // [1, 4096, 1024]
    const float* w_qkv  = (const float*)d_in[1];   // [1536, 1024]
    const float* w_proj = (const float*)d_in[2];   // [1024, 1024]
    const float* q_gain = (const float*)d_in[3];   // [16]
    float* out = (float*)d_out;                    // [4096, 1024]

    // workspace layout (bf16)
    unsigned short* qbf = (unsigned short*)d_ws;              // 4M
    unsigned short* kbf = qbf + (size_t)H * Tq * HD;          // 1M
    unsigned short* vbf = kbf + (size_t)HKV * Tq * HD;        // 1M
    unsigned short* ybf = vbf + (size_t)HKV * Tq * HD;        // 4M
    unsigned short* xbf = ybf + (size_t)Tq * D;               // 4M
    unsigned short* wqkvbf  = xbf + (size_t)Tq * D;           // 1.5M
    unsigned short* wprojbf = wqkvbf + (size_t)NQKV * D;      // 1M

    to_bf16<<<dim3(Tq * D / 1024), 256, 0, stream>>>(x, xbf, Tq * D);
    to_bf16<<<dim3(NQKV * D / 1024), 256, 0, stream>>>(w_qkv, wqkvbf, NQKV * D);
    to_bf16<<<dim3(D * D / 1024), 256, 0, stream>>>(w_proj, wprojbf, D * D);

    gemm_qkv_mfma<<<dim3(Tq / 128, NQKV / 128), 256, 0, stream>>>(xbf, wqkvbf, qbf, kbf, vbf);
    norm_rope<<<dim3((H + HKV) * Tq / 4), 256, 0, stream>>>(qbf, kbf, q_gain);
    attn_mfma<<<dim3(Tq / 64, H), 256, 0, stream>>>(qbf, kbf, vbf, ybf);
    gemm_proj_mfma<<<dim3(Tq / 128, D / 128), 256, 0, stream>>>(ybf, wprojbf, out);
}

// Round 6
// 242.212 us; speedup vs baseline: 12.0935x; 1.1432x over previous
//
#include <hip/hip_runtime.h>
#include <hip/hip_bf16.h>
#include <math.h>

// Problem constants
constexpr int Tq  = 4096;   // sequence length
constexpr int D   = 1024;   // model dim
constexpr int H   = 16;     // query heads
constexpr int HKV = 4;      // kv heads
constexpr int HD  = 64;     // head dim
constexpr int NQKV = D + 2 * HKV * HD;   // 1536

typedef __attribute__((ext_vector_type(8))) short bf16x8;
typedef __attribute__((ext_vector_type(4))) float f32x4;

static __device__ inline unsigned short f2bf(float f) {
    __hip_bfloat16 h = __float2bfloat16(f);
    return *reinterpret_cast<unsigned short*>(&h);
}
static __device__ inline unsigned short rnbf(float f) {   // RN for positive finite
    unsigned int u = __float_as_uint(f);
    return (unsigned short)((u + 0x8000u) >> 16);
}
static __device__ inline float bf2f(unsigned short u) {
    unsigned int x = ((unsigned int)u) << 16;
    return __uint_as_float(x);
}

#define GLOBAL_LOAD_LDS16(g, l)                                                   \
    __builtin_amdgcn_global_load_lds(                                             \
        (const __attribute__((address_space(1))) void*)(g),                       \
        (__attribute__((address_space(3))) void*)(l), 16, 0, 0)

// ---------------------------------------------------------------------------
// fused f32 -> bf16 convert for x, w_qkv, w_proj (one launch)
// ---------------------------------------------------------------------------
__global__ __launch_bounds__(256)
void to_bf16_all(const float* __restrict__ x, const float* __restrict__ wq,
                 const float* __restrict__ wp,
                 unsigned short* __restrict__ xb, unsigned short* __restrict__ wqb,
                 unsigned short* __restrict__ wpb)
{
    const int N1 = Tq * D, N2 = NQKV * D;
    int i = (blockIdx.x * 256 + threadIdx.x) * 4;
    const float* s; unsigned short* d;
    if (i < N1)            { s = x + i;             d = xb + i; }
    else if (i < N1 + N2)  { s = wq + (i - N1);     d = wqb + (i - N1); }
    else                   { s = wp + (i - N1 - N2); d = wpb + (i - N1 - N2); }
    float4 v = *(const float4*)s;
    ushort4 o;
    o.x = f2bf(v.x); o.y = f2bf(v.y); o.z = f2bf(v.z); o.w = f2bf(v.w);
    *(ushort4*)d = o;
}

// ---------------------------------------------------------------------------
// bf16 MFMA GEMM mainloop (m97 structure): C[M,N] = A[M,K] @ B[N,K]^T
// 128x128 tile, BK=32, 4 waves each 64x64.  (verified rounds 3/5)
// ---------------------------------------------------------------------------
#define GEMM_MAINLOOP(Aptr, Bptr, Kdim)                                           \
    __shared__ __align__(16) unsigned short As[128 * 32];                         \
    __shared__ __align__(16) unsigned short Bs[128 * 32];                         \
    const int tid  = threadIdx.x;                                                 \
    const int lane = tid & 63;                                                    \
    const int w    = tid >> 6;                                                    \
    const int l15  = lane & 15, quad = lane >> 4;                                 \
    const int wm   = w >> 1, wn = w & 1;                                          \
    const int m0   = blockIdx.x * 128, n0 = blockIdx.y * 128;                     \
    const int srow   = lane >> 2;                                                 \
    const int schunk = (lane & 3) ^ ((lane >> 3) & 3);                            \
    const int fs     = (quad ^ ((l15 >> 1) & 3)) * 8;                             \
    f32x4 acc[4][4];                                                              \
    _Pragma("unroll")                                                             \
    for (int i = 0; i < 4; ++i)                                                   \
        _Pragma("unroll")                                                         \
        for (int j = 0; j < 4; ++j) acc[i][j] = (f32x4){0.f, 0.f, 0.f, 0.f};      \
    for (int k0 = 0; k0 < (Kdim); k0 += 32) {                                     \
        __syncthreads();                                                          \
        _Pragma("unroll")                                                         \
        for (int it = 0; it < 2; ++it) {                                          \
            const int r = w * 32 + it * 16 + srow;                                \
            GLOBAL_LOAD_LDS16((Aptr) + (size_t)(m0 + r) * (Kdim) + k0 + schunk * 8,\
                              &As[(w * 32 + it * 16) * 32]);                      \
            GLOBAL_LOAD_LDS16((Bptr) + (size_t)(n0 + r) * (Kdim) + k0 + schunk * 8,\
                              &Bs[(w * 32 + it * 16) * 32]);                      \
        }                                                                         \
        __syncthreads();                                                          \
        bf16x8 af[4], bfr[4];                                                     \
        _Pragma("unroll")                                                         \
        for (int i = 0; i < 4; ++i) {                                             \
            af[i]  = *(const bf16x8*)&As[(wm * 64 + i * 16 + l15) * 32 + fs];     \
            bfr[i] = *(const bf16x8*)&Bs[(wn * 64 + i * 16 + l15) * 32 + fs];     \
        }                                                                         \
        _Pragma("unroll")                                                         \
        for (int i = 0; i < 4; ++i)                                               \
            _Pragma("unroll")                                                     \
            for (int j = 0; j < 4; ++j)                                           \
                acc[i][j] = __builtin_amdgcn_mfma_f32_16x16x32_bf16(              \
                    af[i], bfr[j], acc[i][j], 0, 0, 0);                           \
    }

// qkv = x @ w_qkv^T; Q,K bf16 [h][t][d] (pre-norm), V bf16 transposed [hkv][d][t]
__global__ __launch_bounds__(256)
void gemm_qkv_mfma(const unsigned short* __restrict__ A,
                   const unsigned short* __restrict__ B,
                   unsigned short* __restrict__ qbf,
                   unsigned short* __restrict__ kbf,
                   unsigned short* __restrict__ vbf)
{
    GEMM_MAINLOOP(A, B, 1024)
    #pragma unroll
    for (int i = 0; i < 4; ++i) {
        #pragma unroll
        for (int j = 0; j < 4; ++j) {
            const int n = n0 + wn * 64 + j * 16 + l15;
            #pragma unroll
            for (int r = 0; r < 4; ++r) {
                const int t = m0 + wm * 64 + i * 16 + quad * 4 + r;
                const unsigned short v = f2bf(acc[i][j][r]);
                if (n < D) {
                    qbf[((size_t)(n >> 6) * Tq + t) * HD + (n & 63)] = v;
                } else if (n < D + 256) {
                    kbf[((size_t)((n - D) >> 6) * Tq + t) * HD + (n & 63)] = v;
                } else {
                    vbf[((size_t)((n - D - 256) >> 6) * HD + (n & 63)) * Tq + t] = v;
                }
            }
        }
    }
}

// out = y @ w_proj^T  (f32 output)
__global__ __launch_bounds__(256)
void gemm_proj_mfma(const unsigned short* __restrict__ A,
                    const unsigned short* __restrict__ B,
                    float* __restrict__ C)
{
    GEMM_MAINLOOP(A, B, 1024)
    #pragma unroll
    for (int i = 0; i < 4; ++i) {
        #pragma unroll
        for (int j = 0; j < 4; ++j) {
            const int n = n0 + wn * 64 + j * 16 + l15;
            #pragma unroll
            for (int r = 0; r < 4; ++r) {
                const int t = m0 + wm * 64 + i * 16 + quad * 4 + r;
                C[(size_t)t * D + n] = acc[i][j][r];
            }
        }
    }
}

// ---------------------------------------------------------------------------
// Per-row (t, head) RMS norm + rotary + gain, bf16 in/out in place.
// ---------------------------------------------------------------------------
__global__ __launch_bounds__(256)
void norm_rope(unsigned short* __restrict__ qbf, unsigned short* __restrict__ kbf,
               const float* __restrict__ gain)
{
    const int tid  = threadIdx.x;
    const int lane = tid & 63;
    const long row = (long)blockIdx.x * 4 + (tid >> 6);
    const long QROWS = (long)H * Tq;

    unsigned short* base;
    int t;
    float g;
    if (row < QROWS) {
        base = qbf + row * HD;
        t = (int)(row & (Tq - 1));
        g = gain[row >> 12];
    } else {
        const long r2 = row - QROWS;
        base = kbf + r2 * HD;
        t = (int)(r2 & (Tq - 1));
        g = 1.0f;
    }

    float v = bf2f(base[lane]);
    float ss = v * v;
    #pragma unroll
    for (int m = 1; m < 64; m <<= 1) ss += __shfl_xor(ss, m);
    const float rms = rsqrtf(ss * (1.0f / 64.0f) + 1.1920929e-07f);
    const float vn = v * rms;
    const float p = __shfl_xor(vn, 32);

    const int i = lane & 31;
    const float invf = __expf((float)i * -0.28782313662425572f);
    const float ang = (float)t * invf;
    float s, c;
    sincosf(ang, &s, &c);
    const float res = vn * c + ((lane < 32) ? p * s : -(p * s));
    base[lane] = f2bf(res * g);
}

// ---------------------------------------------------------------------------
// Flash attention, bf16 MFMA. Block = (hkv, 32-row q-tile); 4 waves = the 4
// q-heads of this KV group, each wave 32q x 64k per iteration.
// S computed TRANSPOSED (S^T = K Q^T) so P packs into b64 LDS writes and
// reads back as a b128 A-fragment. Static-max softmax p = exp(s/8 - 22)
// (|s|<=64 since q,k are unit-RMS rows); l restored in the epilogue.
// Register-pipelined KV staging (round-5-verified pattern).
// ---------------------------------------------------------------------------
__global__ __launch_bounds__(256, 3)
void attn_mfma(const unsigned short* __restrict__ qbf,
               const unsigned short* __restrict__ kbf,
               const unsigned short* __restrict__ vbf,
               unsigned short* __restrict__ ybf)
{
    __shared__ __align__(16) unsigned short Ks[64 * 72];   // [key][d]
    __shared__ __align__(16) unsigned short Vs[64 * 72];   // [d][key]
    __shared__ __align__(16) unsigned short Ps[4][32 * 72]; // per-wave [q][key]

    const int qt   = 127 - (int)blockIdx.x;   // long blocks first
    const int hkv  = blockIdx.y;
    const int tid  = threadIdx.x;
    const int lane = tid & 63;
    const int w    = tid >> 6;
    const int h    = hkv * 4 + w;             // this wave's query head
    const int l15  = lane & 15;
    const int quad = lane >> 4;
    const int q0   = qt * 32;
    const int nkt  = (qt >> 1) + 1;           // 64-key tiles to process

    const unsigned short* kB = kbf + (size_t)hkv * Tq * HD;
    const unsigned short* vB = vbf + (size_t)hkv * HD * Tq;

    // staging geometry: 256 threads stage the 64x64 K tile and V tile
    const int srow = tid >> 2;           // 0..63
    const int sc   = (tid & 3) * 16;     // column offset in shorts

    // Q fragments as MFMA B-operand: B[k=d][n=q]: lane n=l15, k=quad*8+j
    bf16x8 qf[2][2];
    #pragma unroll
    for (int nt = 0; nt < 2; ++nt)
        #pragma unroll
        for (int ks = 0; ks < 2; ++ks)
            qf[nt][ks] = *(const bf16x8*)(qbf +
                ((size_t)h * Tq + q0 + nt * 16 + l15) * HD + ks * 32 + quad * 8);

    f32x4 o[2][4];     // [q-subtile][d-subtile]
    float lp[2] = {0.f, 0.f};
    #pragma unroll
    for (int i = 0; i < 2; ++i)
        #pragma unroll
        for (int j = 0; j < 4; ++j) o[i][j] = (f32x4){0.f, 0.f, 0.f, 0.f};

    // preload tile 0 into registers
    float4 k0r = *(const float4*)(kB + (size_t)srow * HD + sc);
    float4 k1r = *(const float4*)(kB + (size_t)srow * HD + sc + 8);
    float4 v0r = *(const float4*)(vB + (size_t)srow * Tq + sc);
    float4 v1r = *(const float4*)(vB + (size_t)srow * Tq + sc + 8);

    for (int kt = 0; kt < nkt; ++kt) {
        // stage current tile regs -> LDS (prev iter's reads done: bottom barrier)
        *(float4*)&Ks[srow * 72 + sc]     = k0r;
        *(float4*)&Ks[srow * 72 + sc + 8] = k1r;
        *(float4*)&Vs[srow * 72 + sc]     = v0r;
        *(float4*)&Vs[srow * 72 + sc + 8] = v1r;

        // issue next tile's global loads; vmcnt waited a full phase later
        if (kt + 1 < nkt) {
            const int kbt = (kt + 1) * 64;
            k0r = *(const float4*)(kB + (size_t)(kbt + srow) * HD + sc);
            k1r = *(const float4*)(kB + (size_t)(kbt + srow) * HD + sc + 8);
            v0r = *(const float4*)(vB + (size_t)srow * Tq + kbt + sc);
            v1r = *(const float4*)(vB + (size_t)srow * Tq + kbt + sc + 8);
        }
        __syncthreads();   // tile kt visible to all waves

        // S^T = K Q^T : D[m=key][n=q]; kf (A-frag) reused across both q-tiles
        f32x4 sacc[4][2];
        #pragma unroll
        for (int mt = 0; mt < 4; ++mt)
            #pragma unroll
            for (int nt = 0; nt < 2; ++nt) sacc[mt][nt] = (f32x4){0.f, 0.f, 0.f, 0.f};
        #pragma unroll
        for (int ks = 0; ks < 2; ++ks) {
            #pragma unroll
            for (int mt = 0; mt < 4; ++mt) {
                bf16x8 kf = *(const bf16x8*)&Ks[(mt * 16 + l15) * 72 + quad * 8 + ks * 32];
                #pragma unroll
                for (int nt = 0; nt < 2; ++nt)
                    sacc[mt][nt] = __builtin_amdgcn_mfma_f32_16x16x32_bf16(
                        kf, qf[nt][ks], sacc[mt][nt], 0, 0, 0);
            }
        }

        // softmax: lane holds keys (quad*4+r) x q (l15); 4 keys pack to b64
        if (kt < nkt - 1) {   // fully unmasked tile
            #pragma unroll
            for (int mt = 0; mt < 4; ++mt)
                #pragma unroll
                for (int nt = 0; nt < 2; ++nt) {
                    ushort4 pk;
                    float p0 = __expf(fmaf(sacc[mt][nt][0], 0.125f, -22.0f));
                    float p1 = __expf(fmaf(sacc[mt][nt][1], 0.125f, -22.0f));
                    float p2 = __expf(fmaf(sacc[mt][nt][2], 0.125f, -22.0f));
                    float p3 = __expf(fmaf(sacc[mt][nt][3], 0.125f, -22.0f));
                    lp[nt] += p0 + p1 + p2 + p3;
                    pk.x = rnbf(p0); pk.y = rnbf(p1); pk.z = rnbf(p2); pk.w = rnbf(p3);
                    *(ushort4*)&Ps[w][(nt * 16 + l15) * 72 + mt * 16 + quad * 4] = pk;
                }
        } else {              // diagonal tile: mask key > q
            #pragma unroll
            for (int mt = 0; mt < 4; ++mt)
                #pragma unroll
                for (int nt = 0; nt < 2; ++nt) {
                    const int kglo = kt * 64 + mt * 16 + quad * 4;
                    const int qglo = q0 + nt * 16 + l15;
                    ushort4 pk;
                    float ps = 0.f;
                    float pv[4];
                    #pragma unroll
                    for (int r = 0; r < 4; ++r) {
                        float p = __expf(fmaf(sacc[mt][nt][r], 0.125f, -22.0f));
                        if (kglo + r > qglo) p = 0.f;
                        pv[r] = p; ps += p;
                    }
                    lp[nt] += ps;
                    pk.x = rnbf(pv[0]); pk.y = rnbf(pv[1]);
                    pk.z = rnbf(pv[2]); pk.w = rnbf(pv[3]);
                    *(ushort4*)&Ps[w][(nt * 16 + l15) * 72 + mt * 16 + quad * 4] = pk;
                }
        }

        // O += P V : A-frag from per-wave Ps (b128), B-frag from Vs rows
        #pragma unroll
        for (int ks = 0; ks < 2; ++ks) {
            bf16x8 pf0 = *(const bf16x8*)&Ps[w][(l15) * 72 + quad * 8 + ks * 32];
            bf16x8 pf1 = *(const bf16x8*)&Ps[w][(16 + l15) * 72 + quad * 8 + ks * 32];
            #pragma unroll
            for (int nt = 0; nt < 4; ++nt) {
                bf16x8 vf = *(const bf16x8*)&Vs[(nt * 16 + l15) * 72 + quad * 8 + ks * 32];
                o[0][nt] = __builtin_amdgcn_mfma_f32_16x16x32_bf16(pf0, vf, o[0][nt], 0, 0, 0);
                o[1][nt] = __builtin_amdgcn_mfma_f32_16x16x32_bf16(pf1, vf, o[1][nt], 0, 0, 0);
            }
        }
        __syncthreads();   // all waves done reading Ks/Vs before next staging
    }

    // epilogue: complete l across quads, transpose via per-wave LDS, write y
    float l0 = lp[0], l1 = lp[1];
    l0 += __shfl_xor(l0, 16); l0 += __shfl_xor(l0, 32);
    l1 += __shfl_xor(l1, 16); l1 += __shfl_xor(l1, 32);
    float* Lb = (float*)&Ps[w][0];
    if (quad == 0) { Lb[l15] = l0; Lb[16 + l15] = l1; }
    __syncthreads();
    f32x4 lv0 = *(const f32x4*)&Lb[quad * 4];        // l for q rows 0..15 group
    f32x4 lv1 = *(const f32x4*)&Lb[16 + quad * 4];   // l for q rows 16..31 group
    #pragma unroll
    for (int r = 0; r < 4; ++r) {
        const float i0 = 1.0f / lv0[r];
        const float i1 = 1.0f / lv1[r];
        const int qa = q0 + quad * 4 + r;
        const int qb = qa + 16;
        #pragma unroll
        for (int nt = 0; nt < 4; ++nt) {
            ybf[(size_t)qa * D + h * HD + nt * 16 + l15] = f2bf(o[0][nt][r] * i0);
            ybf[(size_t)qb * D + h * HD + nt * 16 + l15] = f2bf(o[1][nt][r] * i1);
        }
    }
}

// ---------------------------------------------------------------------------
extern "C" void kernel_launch(void* const* d_in, const int* in_sizes, int n_in,
                              void* d_out, int out_size, void* d_ws, size_t ws_size,
                              hipStream_t stream)
{
    const float* x      = (const float*)d_in[0];   // [1, 4096, 1024]
    const float* w_qkv  = (const float*)d_in[1];   // [1536, 1024]
    const float* w_proj = (const float*)d_in[2];   // [1024, 1024]
    const float* q_gain = (const float*)d_in[3];   // [16]
    float* out = (float*)d_out;                    // [4096, 1024]

    // workspace layout (bf16)
    unsigned short* qbf = (unsigned short*)d_ws;              // 4M
    unsigned short* kbf = qbf + (size_t)H * Tq * HD;          // 1M
    unsigned short* vbf = kbf + (size_t)HKV * Tq * HD;        // 1M
    unsigned short* ybf = vbf + (size_t)HKV * Tq * HD;        // 4M
    unsigned short* xbf = ybf + (size_t)Tq * D;               // 4M
    unsigned short* wqkvbf  = xbf + (size_t)Tq * D;           // 1.5M
    unsigned short* wprojbf = wqkvbf + (size_t)NQKV * D;      // 1M

    const int NTOT = Tq * D + NQKV * D + D * D;
    to_bf16_all<<<dim3(NTOT / 1024), 256, 0, stream>>>(x, w_qkv, w_proj,
                                                       xbf, wqkvbf, wprojbf);

    gemm_qkv_mfma<<<dim3(Tq / 128, NQKV / 128), 256, 0, stream>>>(xbf, wqkvbf, qbf, kbf, vbf);
    norm_rope<<<dim3((H + HKV) * Tq / 4), 256, 0, stream>>>(qbf, kbf, q_gain);
    attn_mfma<<<dim3(Tq / 32, HKV), 256, 0, stream>>>(qbf, kbf, vbf, ybf);
    gemm_proj_mfma<<<dim3(Tq / 128, D / 128), 256, 0, stream>>>(ybf, wprojbf, out);
}

// Round 7
// 215.434 us; speedup vs baseline: 13.5967x; 1.1243x over previous
//
#include <hip/hip_runtime.h>
#include <hip/hip_bf16.h>
#include <math.h>

// Problem constants
constexpr int Tq  = 4096;   // sequence length
constexpr int D   = 1024;   // model dim
constexpr int H   = 16;     // query heads
constexpr int HKV = 4;      // kv heads
constexpr int HD  = 64;     // head dim
constexpr int NQKV = D + 2 * HKV * HD;   // 1536

typedef __attribute__((ext_vector_type(8))) short bf16x8;
typedef __attribute__((ext_vector_type(4))) float f32x4;

static __device__ inline unsigned short f2bf(float f) {
    __hip_bfloat16 h = __float2bfloat16(f);
    return *reinterpret_cast<unsigned short*>(&h);
}
static __device__ inline unsigned short rnbf(float f) {   // RN for positive finite
    unsigned int u = __float_as_uint(f);
    return (unsigned short)((u + 0x8000u) >> 16);
}
static __device__ inline float bf2f(unsigned short u) {
    unsigned int x = ((unsigned int)u) << 16;
    return __uint_as_float(x);
}

#define GLOBAL_LOAD_LDS16(g, l)                                                   \
    __builtin_amdgcn_global_load_lds(                                             \
        (const __attribute__((address_space(1))) void*)(g),                       \
        (__attribute__((address_space(3))) void*)(l), 16, 0, 0)

// ---------------------------------------------------------------------------
// fused f32 -> bf16 convert for x, w_qkv, w_proj (one launch)
// ---------------------------------------------------------------------------
__global__ __launch_bounds__(256)
void to_bf16_all(const float* __restrict__ x, const float* __restrict__ wq,
                 const float* __restrict__ wp,
                 unsigned short* __restrict__ xb, unsigned short* __restrict__ wqb,
                 unsigned short* __restrict__ wpb)
{
    const int N1 = Tq * D, N2 = NQKV * D;
    int i = (blockIdx.x * 256 + threadIdx.x) * 4;
    const float* s; unsigned short* d;
    if (i < N1)            { s = x + i;             d = xb + i; }
    else if (i < N1 + N2)  { s = wq + (i - N1);     d = wqb + (i - N1); }
    else                   { s = wp + (i - N1 - N2); d = wpb + (i - N1 - N2); }
    float4 v = *(const float4*)s;
    ushort4 o;
    o.x = f2bf(v.x); o.y = f2bf(v.y); o.z = f2bf(v.z); o.w = f2bf(v.w);
    *(ushort4*)d = o;
}

// ---------------------------------------------------------------------------
// bf16 MFMA GEMM mainloop (m97 structure): C[M,N] = A[M,K] @ B[N,K]^T
// 128x128 tile, BK=32, 4 waves each 64x64.  (verified rounds 3/5/6)
// ---------------------------------------------------------------------------
#define GEMM_MAINLOOP(Aptr, Bptr, Kdim)                                           \
    __shared__ __align__(16) unsigned short As[128 * 32];                         \
    __shared__ __align__(16) unsigned short Bs[128 * 32];                         \
    const int tid  = threadIdx.x;                                                 \
    const int lane = tid & 63;                                                    \
    const int w    = tid >> 6;                                                    \
    const int l15  = lane & 15, quad = lane >> 4;                                 \
    const int wm   = w >> 1, wn = w & 1;                                          \
    const int m0   = blockIdx.x * 128, n0 = blockIdx.y * 128;                     \
    const int srow   = lane >> 2;                                                 \
    const int schunk = (lane & 3) ^ ((lane >> 3) & 3);                            \
    const int fs     = (quad ^ ((l15 >> 1) & 3)) * 8;                             \
    f32x4 acc[4][4];                                                              \
    _Pragma("unroll")                                                             \
    for (int i = 0; i < 4; ++i)                                                   \
        _Pragma("unroll")                                                         \
        for (int j = 0; j < 4; ++j) acc[i][j] = (f32x4){0.f, 0.f, 0.f, 0.f};      \
    for (int k0 = 0; k0 < (Kdim); k0 += 32) {                                     \
        __syncthreads();                                                          \
        _Pragma("unroll")                                                         \
        for (int it = 0; it < 2; ++it) {                                          \
            const int r = w * 32 + it * 16 + srow;                                \
            GLOBAL_LOAD_LDS16((Aptr) + (size_t)(m0 + r) * (Kdim) + k0 + schunk * 8,\
                              &As[(w * 32 + it * 16) * 32]);                      \
            GLOBAL_LOAD_LDS16((Bptr) + (size_t)(n0 + r) * (Kdim) + k0 + schunk * 8,\
                              &Bs[(w * 32 + it * 16) * 32]);                      \
        }                                                                         \
        __syncthreads();                                                          \
        bf16x8 af[4], bfr[4];                                                     \
        _Pragma("unroll")                                                         \
        for (int i = 0; i < 4; ++i) {                                             \
            af[i]  = *(const bf16x8*)&As[(wm * 64 + i * 16 + l15) * 32 + fs];     \
            bfr[i] = *(const bf16x8*)&Bs[(wn * 64 + i * 16 + l15) * 32 + fs];     \
        }                                                                         \
        _Pragma("unroll")                                                         \
        for (int i = 0; i < 4; ++i)                                               \
            _Pragma("unroll")                                                     \
            for (int j = 0; j < 4; ++j)                                           \
                acc[i][j] = __builtin_amdgcn_mfma_f32_16x16x32_bf16(              \
                    af[i], bfr[j], acc[i][j], 0, 0, 0);                           \
    }

// qkv = x @ w_qkv^T; Q,K bf16 [h][t][d] (pre-norm), V bf16 transposed [hkv][d][t]
__global__ __launch_bounds__(256)
void gemm_qkv_mfma(const unsigned short* __restrict__ A,
                   const unsigned short* __restrict__ B,
                   unsigned short* __restrict__ qbf,
                   unsigned short* __restrict__ kbf,
                   unsigned short* __restrict__ vbf)
{
    GEMM_MAINLOOP(A, B, 1024)
    #pragma unroll
    for (int i = 0; i < 4; ++i) {
        #pragma unroll
        for (int j = 0; j < 4; ++j) {
            const int n = n0 + wn * 64 + j * 16 + l15;
            #pragma unroll
            for (int r = 0; r < 4; ++r) {
                const int t = m0 + wm * 64 + i * 16 + quad * 4 + r;
                const unsigned short v = f2bf(acc[i][j][r]);
                if (n < D) {
                    qbf[((size_t)(n >> 6) * Tq + t) * HD + (n & 63)] = v;
                } else if (n < D + 256) {
                    kbf[((size_t)((n - D) >> 6) * Tq + t) * HD + (n & 63)] = v;
                } else {
                    vbf[((size_t)((n - D - 256) >> 6) * HD + (n & 63)) * Tq + t] = v;
                }
            }
        }
    }
}

// out = y @ w_proj^T  (f32 output)
__global__ __launch_bounds__(256)
void gemm_proj_mfma(const unsigned short* __restrict__ A,
                    const unsigned short* __restrict__ B,
                    float* __restrict__ C)
{
    GEMM_MAINLOOP(A, B, 1024)
    #pragma unroll
    for (int i = 0; i < 4; ++i) {
        #pragma unroll
        for (int j = 0; j < 4; ++j) {
            const int n = n0 + wn * 64 + j * 16 + l15;
            #pragma unroll
            for (int r = 0; r < 4; ++r) {
                const int t = m0 + wm * 64 + i * 16 + quad * 4 + r;
                C[(size_t)t * D + n] = acc[i][j][r];
            }
        }
    }
}

// ---------------------------------------------------------------------------
// Per-row (t, head) RMS norm + rotary + gain, bf16 in/out in place.
// ---------------------------------------------------------------------------
__global__ __launch_bounds__(256)
void norm_rope(unsigned short* __restrict__ qbf, unsigned short* __restrict__ kbf,
               const float* __restrict__ gain)
{
    const int tid  = threadIdx.x;
    const int lane = tid & 63;
    const long row = (long)blockIdx.x * 4 + (tid >> 6);
    const long QROWS = (long)H * Tq;

    unsigned short* base;
    int t;
    float g;
    if (row < QROWS) {
        base = qbf + row * HD;
        t = (int)(row & (Tq - 1));
        g = gain[row >> 12];
    } else {
        const long r2 = row - QROWS;
        base = kbf + r2 * HD;
        t = (int)(r2 & (Tq - 1));
        g = 1.0f;
    }

    float v = bf2f(base[lane]);
    float ss = v * v;
    #pragma unroll
    for (int m = 1; m < 64; m <<= 1) ss += __shfl_xor(ss, m);
    const float rms = rsqrtf(ss * (1.0f / 64.0f) + 1.1920929e-07f);
    const float vn = v * rms;
    const float p = __shfl_xor(vn, 32);

    const int i = lane & 31;
    const float invf = __expf((float)i * -0.28782313662425572f);
    const float ang = (float)t * invf;
    float s, c;
    sincosf(ang, &s, &c);
    const float res = vn * c + ((lane < 32) ? p * s : -(p * s));
    base[lane] = f2bf(res * g);
}

// ---------------------------------------------------------------------------
// Flash attention, bf16 MFMA. Block = (hkv, 32-row q-tile); 4 waves = the 4
// q-heads of this KV group, each wave 32q x 64k per iteration.
// S computed TRANSPOSED (S^T = K Q^T) so P packs into b64 LDS writes and
// reads back as a b128 A-fragment. Static-max softmax p = exp(s/8 - 22)
// (|s|<=64 since q,k are unit-RMS rows); l restored in the epilogue.
// Register-pipelined KV staging (round-5-verified pattern).
//
// LOAD BALANCE: co-resident blocks are ids c and c+256 (same bx). Map
// qt = bx for hkv>=2 and qt = 127-bx for hkv<2 so every CU's pair does
// complementary (long+short) work: ~65.5 tile-units per CU, constant.
// ---------------------------------------------------------------------------
__global__ __launch_bounds__(256, 3)
void attn_mfma(const unsigned short* __restrict__ qbf,
               const unsigned short* __restrict__ kbf,
               const unsigned short* __restrict__ vbf,
               unsigned short* __restrict__ ybf)
{
    __shared__ __align__(16) unsigned short Ks[64 * 72];   // [key][d]
    __shared__ __align__(16) unsigned short Vs[64 * 72];   // [d][key]
    __shared__ __align__(16) unsigned short Ps[4][32 * 72]; // per-wave [q][key]

    const int hkv  = blockIdx.y;
    const int bx   = (int)blockIdx.x;
    const int qt   = (hkv >= 2) ? bx : (127 - bx);   // complementary pairing
    const int tid  = threadIdx.x;
    const int lane = tid & 63;
    const int w    = tid >> 6;
    const int h    = hkv * 4 + w;             // this wave's query head
    const int l15  = lane & 15;
    const int quad = lane >> 4;
    const int q0   = qt * 32;
    const int nkt  = (qt >> 1) + 1;           // 64-key tiles to process

    const unsigned short* kB = kbf + (size_t)hkv * Tq * HD;
    const unsigned short* vB = vbf + (size_t)hkv * HD * Tq;

    // staging geometry: 256 threads stage the 64x64 K tile and V tile
    const int srow = tid >> 2;           // 0..63
    const int sc   = (tid & 3) * 16;     // column offset in shorts

    // Q fragments as MFMA B-operand: B[k=d][n=q]: lane n=l15, k=quad*8+j
    bf16x8 qf[2][2];
    #pragma unroll
    for (int nt = 0; nt < 2; ++nt)
        #pragma unroll
        for (int ks = 0; ks < 2; ++ks)
            qf[nt][ks] = *(const bf16x8*)(qbf +
                ((size_t)h * Tq + q0 + nt * 16 + l15) * HD + ks * 32 + quad * 8);

    f32x4 o[2][4];     // [q-subtile][d-subtile]
    float lp[2] = {0.f, 0.f};
    #pragma unroll
    for (int i = 0; i < 2; ++i)
        #pragma unroll
        for (int j = 0; j < 4; ++j) o[i][j] = (f32x4){0.f, 0.f, 0.f, 0.f};

    // preload tile 0 into registers
    float4 k0r = *(const float4*)(kB + (size_t)srow * HD + sc);
    float4 k1r = *(const float4*)(kB + (size_t)srow * HD + sc + 8);
    float4 v0r = *(const float4*)(vB + (size_t)srow * Tq + sc);
    float4 v1r = *(const float4*)(vB + (size_t)srow * Tq + sc + 8);

    for (int kt = 0; kt < nkt; ++kt) {
        // stage current tile regs -> LDS (prev iter's reads done: bottom barrier)
        *(float4*)&Ks[srow * 72 + sc]     = k0r;
        *(float4*)&Ks[srow * 72 + sc + 8] = k1r;
        *(float4*)&Vs[srow * 72 + sc]     = v0r;
        *(float4*)&Vs[srow * 72 + sc + 8] = v1r;

        // issue next tile's global loads; vmcnt waited a full phase later
        if (kt + 1 < nkt) {
            const int kbt = (kt + 1) * 64;
            k0r = *(const float4*)(kB + (size_t)(kbt + srow) * HD + sc);
            k1r = *(const float4*)(kB + (size_t)(kbt + srow) * HD + sc + 8);
            v0r = *(const float4*)(vB + (size_t)srow * Tq + kbt + sc);
            v1r = *(const float4*)(vB + (size_t)srow * Tq + kbt + sc + 8);
        }
        __syncthreads();   // tile kt visible to all waves

        // S^T = K Q^T : D[m=key][n=q]; kf (A-frag) reused across both q-tiles
        f32x4 sacc[4][2];
        #pragma unroll
        for (int mt = 0; mt < 4; ++mt)
            #pragma unroll
            for (int nt = 0; nt < 2; ++nt) sacc[mt][nt] = (f32x4){0.f, 0.f, 0.f, 0.f};
        #pragma unroll
        for (int ks = 0; ks < 2; ++ks) {
            #pragma unroll
            for (int mt = 0; mt < 4; ++mt) {
                bf16x8 kf = *(const bf16x8*)&Ks[(mt * 16 + l15) * 72 + quad * 8 + ks * 32];
                #pragma unroll
                for (int nt = 0; nt < 2; ++nt)
                    sacc[mt][nt] = __builtin_amdgcn_mfma_f32_16x16x32_bf16(
                        kf, qf[nt][ks], sacc[mt][nt], 0, 0, 0);
            }
        }

        // softmax: lane holds keys (quad*4+r) x q (l15); 4 keys pack to b64
        if (kt < nkt - 1) {   // fully unmasked tile
            #pragma unroll
            for (int mt = 0; mt < 4; ++mt)
                #pragma unroll
                for (int nt = 0; nt < 2; ++nt) {
                    ushort4 pk;
                    float p0 = __expf(fmaf(sacc[mt][nt][0], 0.125f, -22.0f));
                    float p1 = __expf(fmaf(sacc[mt][nt][1], 0.125f, -22.0f));
                    float p2 = __expf(fmaf(sacc[mt][nt][2], 0.125f, -22.0f));
                    float p3 = __expf(fmaf(sacc[mt][nt][3], 0.125f, -22.0f));
                    lp[nt] += p0 + p1 + p2 + p3;
                    pk.x = rnbf(p0); pk.y = rnbf(p1); pk.z = rnbf(p2); pk.w = rnbf(p3);
                    *(ushort4*)&Ps[w][(nt * 16 + l15) * 72 + mt * 16 + quad * 4] = pk;
                }
        } else {              // diagonal tile: mask key > q
            #pragma unroll
            for (int mt = 0; mt < 4; ++mt)
                #pragma unroll
                for (int nt = 0; nt < 2; ++nt) {
                    const int kglo = kt * 64 + mt * 16 + quad * 4;
                    const int qglo = q0 + nt * 16 + l15;
                    ushort4 pk;
                    float ps = 0.f;
                    float pv[4];
                    #pragma unroll
                    for (int r = 0; r < 4; ++r) {
                        float p = __expf(fmaf(sacc[mt][nt][r], 0.125f, -22.0f));
                        if (kglo + r > qglo) p = 0.f;
                        pv[r] = p; ps += p;
                    }
                    lp[nt] += ps;
                    pk.x = rnbf(pv[0]); pk.y = rnbf(pv[1]);
                    pk.z = rnbf(pv[2]); pk.w = rnbf(pv[3]);
                    *(ushort4*)&Ps[w][(nt * 16 + l15) * 72 + mt * 16 + quad * 4] = pk;
                }
        }

        // O += P V : A-frag from per-wave Ps (b128), B-frag from Vs rows
        #pragma unroll
        for (int ks = 0; ks < 2; ++ks) {
            bf16x8 pf0 = *(const bf16x8*)&Ps[w][(l15) * 72 + quad * 8 + ks * 32];
            bf16x8 pf1 = *(const bf16x8*)&Ps[w][(16 + l15) * 72 + quad * 8 + ks * 32];
            #pragma unroll
            for (int nt = 0; nt < 4; ++nt) {
                bf16x8 vf = *(const bf16x8*)&Vs[(nt * 16 + l15) * 72 + quad * 8 + ks * 32];
                o[0][nt] = __builtin_amdgcn_mfma_f32_16x16x32_bf16(pf0, vf, o[0][nt], 0, 0, 0);
                o[1][nt] = __builtin_amdgcn_mfma_f32_16x16x32_bf16(pf1, vf, o[1][nt], 0, 0, 0);
            }
        }
        __syncthreads();   // all waves done reading Ks/Vs before next staging
    }

    // epilogue: complete l across quads, transpose via per-wave LDS, write y
    float l0 = lp[0], l1 = lp[1];
    l0 += __shfl_xor(l0, 16); l0 += __shfl_xor(l0, 32);
    l1 += __shfl_xor(l1, 16); l1 += __shfl_xor(l1, 32);
    float* Lb = (float*)&Ps[w][0];
    if (quad == 0) { Lb[l15] = l0; Lb[16 + l15] = l1; }
    __syncthreads();
    f32x4 lv0 = *(const f32x4*)&Lb[quad * 4];        // l for q rows 0..15 group
    f32x4 lv1 = *(const f32x4*)&Lb[16 + quad * 4];   // l for q rows 16..31 group
    #pragma unroll
    for (int r = 0; r < 4; ++r) {
        const float i0 = 1.0f / lv0[r];
        const float i1 = 1.0f / lv1[r];
        const int qa = q0 + quad * 4 + r;
        const int qb = qa + 16;
        #pragma unroll
        for (int nt = 0; nt < 4; ++nt) {
            ybf[(size_t)qa * D + h * HD + nt * 16 + l15] = f2bf(o[0][nt][r] * i0);
            ybf[(size_t)qb * D + h * HD + nt * 16 + l15] = f2bf(o[1][nt][r] * i1);
        }
    }
}

// ---------------------------------------------------------------------------
extern "C" void kernel_launch(void* const* d_in, const int* in_sizes, int n_in,
                              void* d_out, int out_size, void* d_ws, size_t ws_size,
                              hipStream_t stream)
{
    const float* x      = (const float*)d_in[0];   // [1, 4096, 1024]
    const float* w_qkv  = (const float*)d_in[1];   // [1536, 1024]
    const float* w_proj = (const float*)d_in[2];   // [1024, 1024]
    const float* q_gain = (const float*)d_in[3];   // [16]
    float* out = (float*)d_out;                    // [4096, 1024]

    // workspace layout (bf16)
    unsigned short* qbf = (unsigned short*)d_ws;              // 4M
    unsigned short* kbf = qbf + (size_t)H * Tq * HD;          // 1M
    unsigned short* vbf = kbf + (size_t)HKV * Tq * HD;        // 1M
    unsigned short* ybf = vbf + (size_t)HKV * Tq * HD;        // 4M
    unsigned short* xbf = ybf + (size_t)Tq * D;               // 4M
    unsigned short* wqkvbf  = xbf + (size_t)Tq * D;           // 1.5M
    unsigned short* wprojbf = wqkvbf + (size_t)NQKV * D;      // 1M

    const int NTOT = Tq * D + NQKV * D + D * D;
    to_bf16_all<<<dim3(NTOT / 1024), 256, 0, stream>>>(x, w_qkv, w_proj,
                                                       xbf, wqkvbf, wprojbf);

    gemm_qkv_mfma<<<dim3(Tq / 128, NQKV / 128), 256, 0, stream>>>(xbf, wqkvbf, qbf, kbf, vbf);
    norm_rope<<<dim3((H + HKV) * Tq / 4), 256, 0, stream>>>(qbf, kbf, q_gain);
    attn_mfma<<<dim3(Tq / 32, HKV), 256, 0, stream>>>(qbf, kbf, vbf, ybf);
    gemm_proj_mfma<<<dim3(Tq / 128, D / 128), 256, 0, stream>>>(ybf, wprojbf, out);
}

// Round 8
// 203.311 us; speedup vs baseline: 14.4075x; 1.0596x over previous
//
#include <hip/hip_runtime.h>
#include <hip/hip_bf16.h>
#include <math.h>

// Problem constants
constexpr int Tq  = 4096;   // sequence length
constexpr int D   = 1024;   // model dim
constexpr int H   = 16;     // query heads
constexpr int HKV = 4;      // kv heads
constexpr int HD  = 64;     // head dim
constexpr int NQKV = D + 2 * HKV * HD;   // 1536

typedef __attribute__((ext_vector_type(8))) short bf16x8;
typedef __attribute__((ext_vector_type(4))) float f32x4;

static __device__ inline unsigned short f2bf(float f) {
    __hip_bfloat16 h = __float2bfloat16(f);
    return *reinterpret_cast<unsigned short*>(&h);
}
static __device__ inline unsigned short rnbf(float f) {   // RN for positive finite
    unsigned int u = __float_as_uint(f);
    return (unsigned short)((u + 0x8000u) >> 16);
}
static __device__ inline float bf2f(unsigned short u) {
    unsigned int x = ((unsigned int)u) << 16;
    return __uint_as_float(x);
}

#define GLOBAL_LOAD_LDS16(g, l)                                                   \
    __builtin_amdgcn_global_load_lds(                                             \
        (const __attribute__((address_space(1))) void*)(g),                       \
        (__attribute__((address_space(3))) void*)(l), 16, 0, 0)

// ---------------------------------------------------------------------------
// fused f32 -> bf16 convert for x, w_qkv, w_proj (one launch)
// ---------------------------------------------------------------------------
__global__ __launch_bounds__(256)
void to_bf16_all(const float* __restrict__ x, const float* __restrict__ wq,
                 const float* __restrict__ wp,
                 unsigned short* __restrict__ xb, unsigned short* __restrict__ wqb,
                 unsigned short* __restrict__ wpb)
{
    const int N1 = Tq * D, N2 = NQKV * D;
    int i = (blockIdx.x * 256 + threadIdx.x) * 4;
    const float* s; unsigned short* d;
    if (i < N1)            { s = x + i;             d = xb + i; }
    else if (i < N1 + N2)  { s = wq + (i - N1);     d = wqb + (i - N1); }
    else                   { s = wp + (i - N1 - N2); d = wpb + (i - N1 - N2); }
    float4 v = *(const float4*)s;
    ushort4 o;
    o.x = f2bf(v.x); o.y = f2bf(v.y); o.z = f2bf(v.z); o.w = f2bf(v.w);
    *(ushort4*)d = o;
}

// ---------------------------------------------------------------------------
// bf16 MFMA GEMM mainloop (m97 structure): C[M,N] = A[M,K] @ B[N,K]^T
// 128x128 tile, BK=32, 4 waves each 64x64.  (verified rounds 3/5/6/7)
// ---------------------------------------------------------------------------
#define GEMM_MAINLOOP(Aptr, Bptr, Kdim)                                           \
    __shared__ __align__(16) unsigned short As[128 * 32];                         \
    __shared__ __align__(16) unsigned short Bs[128 * 32];                         \
    const int tid  = threadIdx.x;                                                 \
    const int lane = tid & 63;                                                    \
    const int w    = tid >> 6;                                                    \
    const int l15  = lane & 15, quad = lane >> 4;                                 \
    const int wm   = w >> 1, wn = w & 1;                                          \
    const int m0   = blockIdx.x * 128, n0 = blockIdx.y * 128;                     \
    const int srow   = lane >> 2;                                                 \
    const int schunk = (lane & 3) ^ ((lane >> 3) & 3);                            \
    const int fs     = (quad ^ ((l15 >> 1) & 3)) * 8;                             \
    f32x4 acc[4][4];                                                              \
    _Pragma("unroll")                                                             \
    for (int i = 0; i < 4; ++i)                                                   \
        _Pragma("unroll")                                                         \
        for (int j = 0; j < 4; ++j) acc[i][j] = (f32x4){0.f, 0.f, 0.f, 0.f};      \
    for (int k0 = 0; k0 < (Kdim); k0 += 32) {                                     \
        __syncthreads();                                                          \
        _Pragma("unroll")                                                         \
        for (int it = 0; it < 2; ++it) {                                          \
            const int r = w * 32 + it * 16 + srow;                                \
            GLOBAL_LOAD_LDS16((Aptr) + (size_t)(m0 + r) * (Kdim) + k0 + schunk * 8,\
                              &As[(w * 32 + it * 16) * 32]);                      \
            GLOBAL_LOAD_LDS16((Bptr) + (size_t)(n0 + r) * (Kdim) + k0 + schunk * 8,\
                              &Bs[(w * 32 + it * 16) * 32]);                      \
        }                                                                         \
        __syncthreads();                                                          \
        bf16x8 af[4], bfr[4];                                                     \
        _Pragma("unroll")                                                         \
        for (int i = 0; i < 4; ++i) {                                             \
            af[i]  = *(const bf16x8*)&As[(wm * 64 + i * 16 + l15) * 32 + fs];     \
            bfr[i] = *(const bf16x8*)&Bs[(wn * 64 + i * 16 + l15) * 32 + fs];     \
        }                                                                         \
        _Pragma("unroll")                                                         \
        for (int i = 0; i < 4; ++i)                                               \
            _Pragma("unroll")                                                     \
            for (int j = 0; j < 4; ++j)                                           \
                acc[i][j] = __builtin_amdgcn_mfma_f32_16x16x32_bf16(              \
                    af[i], bfr[j], acc[i][j], 0, 0, 0);                           \
    }

// qkv = x @ w_qkv^T; Q,K bf16 [h][t][d] (pre-norm), V bf16 transposed [hkv][d][t]
__global__ __launch_bounds__(256)
void gemm_qkv_mfma(const unsigned short* __restrict__ A,
                   const unsigned short* __restrict__ B,
                   unsigned short* __restrict__ qbf,
                   unsigned short* __restrict__ kbf,
                   unsigned short* __restrict__ vbf)
{
    GEMM_MAINLOOP(A, B, 1024)
    #pragma unroll
    for (int i = 0; i < 4; ++i) {
        #pragma unroll
        for (int j = 0; j < 4; ++j) {
            const int n = n0 + wn * 64 + j * 16 + l15;
            #pragma unroll
            for (int r = 0; r < 4; ++r) {
                const int t = m0 + wm * 64 + i * 16 + quad * 4 + r;
                const unsigned short v = f2bf(acc[i][j][r]);
                if (n < D) {
                    qbf[((size_t)(n >> 6) * Tq + t) * HD + (n & 63)] = v;
                } else if (n < D + 256) {
                    kbf[((size_t)((n - D) >> 6) * Tq + t) * HD + (n & 63)] = v;
                } else {
                    vbf[((size_t)((n - D - 256) >> 6) * HD + (n & 63)) * Tq + t] = v;
                }
            }
        }
    }
}

// out = y @ w_proj^T  (f32 output)
__global__ __launch_bounds__(256)
void gemm_proj_mfma(const unsigned short* __restrict__ A,
                    const unsigned short* __restrict__ B,
                    float* __restrict__ C)
{
    GEMM_MAINLOOP(A, B, 1024)
    #pragma unroll
    for (int i = 0; i < 4; ++i) {
        #pragma unroll
        for (int j = 0; j < 4; ++j) {
            const int n = n0 + wn * 64 + j * 16 + l15;
            #pragma unroll
            for (int r = 0; r < 4; ++r) {
                const int t = m0 + wm * 64 + i * 16 + quad * 4 + r;
                C[(size_t)t * D + n] = acc[i][j][r];
            }
        }
    }
}

// ---------------------------------------------------------------------------
// Per-row (t, head) RMS norm + rotary + gain, bf16 in/out in place.
// ---------------------------------------------------------------------------
__global__ __launch_bounds__(256)
void norm_rope(unsigned short* __restrict__ qbf, unsigned short* __restrict__ kbf,
               const float* __restrict__ gain)
{
    const int tid  = threadIdx.x;
    const int lane = tid & 63;
    const long row = (long)blockIdx.x * 4 + (tid >> 6);
    const long QROWS = (long)H * Tq;

    unsigned short* base;
    int t;
    float g;
    if (row < QROWS) {
        base = qbf + row * HD;
        t = (int)(row & (Tq - 1));
        g = gain[row >> 12];
    } else {
        const long r2 = row - QROWS;
        base = kbf + r2 * HD;
        t = (int)(r2 & (Tq - 1));
        g = 1.0f;
    }

    float v = bf2f(base[lane]);
    float ss = v * v;
    #pragma unroll
    for (int m = 1; m < 64; m <<= 1) ss += __shfl_xor(ss, m);
    const float rms = rsqrtf(ss * (1.0f / 64.0f) + 1.1920929e-07f);
    const float vn = v * rms;
    const float p = __shfl_xor(vn, 32);

    const int i = lane & 31;
    const float invf = __expf((float)i * -0.28782313662425572f);
    const float ang = (float)t * invf;
    float s, c;
    sincosf(ang, &s, &c);
    const float res = vn * c + ((lane < 32) ? p * s : -(p * s));
    base[lane] = f2bf(res * g);
}

// ---------------------------------------------------------------------------
// Flash attention, bf16 MFMA. Core loop identical to rounds 5-7 (verified).
//
// EQUAL-WORK TRIPLES: grid (256,3). blockIdx.x = hkv*64 + j; s = blockIdx.y.
//   s=0/1: the two key-range halves of long q-tile qt = 64+j (work ~16.5 ea)
//   s=2  : solo short q-tile qt = 63-j            (work (63-j)/2+1)
// Each CU's triple (same bx, s=0,1,2) sums to ~65.5 tile-units, members <=32.
// Static-max softmax (p = exp(s/8-22)) makes key-partials associative:
// split pieces write raw bf16 o + f32 l to partial buffers; merge_tail sums,
// normalizes, and writes ybf rows 2048+. Solos normalize in-kernel as before.
// ---------------------------------------------------------------------------
__global__ __launch_bounds__(256, 3)
void attn_mfma(const unsigned short* __restrict__ qbf,
               const unsigned short* __restrict__ kbf,
               const unsigned short* __restrict__ vbf,
               unsigned short* __restrict__ ybf,
               unsigned short* __restrict__ oA, unsigned short* __restrict__ oB,
               float* __restrict__ lA, float* __restrict__ lB)
{
    __shared__ __align__(16) unsigned short Ks[64 * 72];   // [key][d]
    __shared__ __align__(16) unsigned short Vs[64 * 72];   // [d][key]
    __shared__ __align__(16) unsigned short Ps[4][32 * 72]; // per-wave [q][key]

    const int s    = blockIdx.y;              // 0,1 = split halves; 2 = solo
    const int hkv  = blockIdx.x >> 6;
    const int j    = blockIdx.x & 63;
    const int qt   = (s == 2) ? (63 - j) : (64 + j);
    const int nkt  = (qt >> 1) + 1;
    const int h0   = nkt >> 1;
    const int k_begin = (s == 1) ? h0 : 0;
    const int k_end   = (s == 0) ? h0 : nkt;

    const int tid  = threadIdx.x;
    const int lane = tid & 63;
    const int w    = tid >> 6;
    const int h    = hkv * 4 + w;             // this wave's query head
    const int l15  = lane & 15;
    const int quad = lane >> 4;
    const int q0   = qt * 32;

    const unsigned short* kB = kbf + (size_t)hkv * Tq * HD;
    const unsigned short* vB = vbf + (size_t)hkv * HD * Tq;

    // staging geometry: 256 threads stage the 64x64 K tile and V tile
    const int srow = tid >> 2;           // 0..63
    const int sc   = (tid & 3) * 16;     // column offset in shorts

    // Q fragments as MFMA B-operand: B[k=d][n=q]: lane n=l15, k=quad*8+j
    bf16x8 qf[2][2];
    #pragma unroll
    for (int nt = 0; nt < 2; ++nt)
        #pragma unroll
        for (int ks = 0; ks < 2; ++ks)
            qf[nt][ks] = *(const bf16x8*)(qbf +
                ((size_t)h * Tq + q0 + nt * 16 + l15) * HD + ks * 32 + quad * 8);

    f32x4 o[2][4];     // [q-subtile][d-subtile]
    float lp[2] = {0.f, 0.f};
    #pragma unroll
    for (int i = 0; i < 2; ++i)
        #pragma unroll
        for (int jj = 0; jj < 4; ++jj) o[i][jj] = (f32x4){0.f, 0.f, 0.f, 0.f};

    // preload tile k_begin into registers
    float4 k0r = *(const float4*)(kB + (size_t)(k_begin * 64 + srow) * HD + sc);
    float4 k1r = *(const float4*)(kB + (size_t)(k_begin * 64 + srow) * HD + sc + 8);
    float4 v0r = *(const float4*)(vB + (size_t)srow * Tq + k_begin * 64 + sc);
    float4 v1r = *(const float4*)(vB + (size_t)srow * Tq + k_begin * 64 + sc + 8);

    for (int kt = k_begin; kt < k_end; ++kt) {
        // stage current tile regs -> LDS (prev iter's reads done: bottom barrier)
        *(float4*)&Ks[srow * 72 + sc]     = k0r;
        *(float4*)&Ks[srow * 72 + sc + 8] = k1r;
        *(float4*)&Vs[srow * 72 + sc]     = v0r;
        *(float4*)&Vs[srow * 72 + sc + 8] = v1r;

        // issue next tile's global loads; vmcnt waited a full phase later
        if (kt + 1 < k_end) {
            const int kbt = (kt + 1) * 64;
            k0r = *(const float4*)(kB + (size_t)(kbt + srow) * HD + sc);
            k1r = *(const float4*)(kB + (size_t)(kbt + srow) * HD + sc + 8);
            v0r = *(const float4*)(vB + (size_t)srow * Tq + kbt + sc);
            v1r = *(const float4*)(vB + (size_t)srow * Tq + kbt + sc + 8);
        }
        __syncthreads();   // tile kt visible to all waves

        // S^T = K Q^T : D[m=key][n=q]; kf (A-frag) reused across both q-tiles
        f32x4 sacc[4][2];
        #pragma unroll
        for (int mt = 0; mt < 4; ++mt)
            #pragma unroll
            for (int nt = 0; nt < 2; ++nt) sacc[mt][nt] = (f32x4){0.f, 0.f, 0.f, 0.f};
        #pragma unroll
        for (int ks = 0; ks < 2; ++ks) {
            #pragma unroll
            for (int mt = 0; mt < 4; ++mt) {
                bf16x8 kf = *(const bf16x8*)&Ks[(mt * 16 + l15) * 72 + quad * 8 + ks * 32];
                #pragma unroll
                for (int nt = 0; nt < 2; ++nt)
                    sacc[mt][nt] = __builtin_amdgcn_mfma_f32_16x16x32_bf16(
                        kf, qf[nt][ks], sacc[mt][nt], 0, 0, 0);
            }
        }

        // softmax: lane holds keys (quad*4+r) x q (l15); 4 keys pack to b64
        if (kt < nkt - 1) {   // fully unmasked tile
            #pragma unroll
            for (int mt = 0; mt < 4; ++mt)
                #pragma unroll
                for (int nt = 0; nt < 2; ++nt) {
                    ushort4 pk;
                    float p0 = __expf(fmaf(sacc[mt][nt][0], 0.125f, -22.0f));
                    float p1 = __expf(fmaf(sacc[mt][nt][1], 0.125f, -22.0f));
                    float p2 = __expf(fmaf(sacc[mt][nt][2], 0.125f, -22.0f));
                    float p3 = __expf(fmaf(sacc[mt][nt][3], 0.125f, -22.0f));
                    lp[nt] += p0 + p1 + p2 + p3;
                    pk.x = rnbf(p0); pk.y = rnbf(p1); pk.z = rnbf(p2); pk.w = rnbf(p3);
                    *(ushort4*)&Ps[w][(nt * 16 + l15) * 72 + mt * 16 + quad * 4] = pk;
                }
        } else {              // diagonal tile: mask key > q
            #pragma unroll
            for (int mt = 0; mt < 4; ++mt)
                #pragma unroll
                for (int nt = 0; nt < 2; ++nt) {
                    const int kglo = kt * 64 + mt * 16 + quad * 4;
                    const int qglo = q0 + nt * 16 + l15;
                    ushort4 pk;
                    float ps = 0.f;
                    float pv[4];
                    #pragma unroll
                    for (int r = 0; r < 4; ++r) {
                        float p = __expf(fmaf(sacc[mt][nt][r], 0.125f, -22.0f));
                        if (kglo + r > qglo) p = 0.f;
                        pv[r] = p; ps += p;
                    }
                    lp[nt] += ps;
                    pk.x = rnbf(pv[0]); pk.y = rnbf(pv[1]);
                    pk.z = rnbf(pv[2]); pk.w = rnbf(pv[3]);
                    *(ushort4*)&Ps[w][(nt * 16 + l15) * 72 + mt * 16 + quad * 4] = pk;
                }
        }

        // O += P V : A-frag from per-wave Ps (b128), B-frag from Vs rows
        #pragma unroll
        for (int ks = 0; ks < 2; ++ks) {
            bf16x8 pf0 = *(const bf16x8*)&Ps[w][(l15) * 72 + quad * 8 + ks * 32];
            bf16x8 pf1 = *(const bf16x8*)&Ps[w][(16 + l15) * 72 + quad * 8 + ks * 32];
            #pragma unroll
            for (int nt = 0; nt < 4; ++nt) {
                bf16x8 vf = *(const bf16x8*)&Vs[(nt * 16 + l15) * 72 + quad * 8 + ks * 32];
                o[0][nt] = __builtin_amdgcn_mfma_f32_16x16x32_bf16(pf0, vf, o[0][nt], 0, 0, 0);
                o[1][nt] = __builtin_amdgcn_mfma_f32_16x16x32_bf16(pf1, vf, o[1][nt], 0, 0, 0);
            }
        }
        __syncthreads();   // all waves done reading Ks/Vs before next staging
    }

    if (s < 2) {
        // split piece: raw bf16 o-partials + f32 l (no normalize; associative)
        float l0 = lp[0], l1 = lp[1];
        l0 += __shfl_xor(l0, 16); l0 += __shfl_xor(l0, 32);
        l1 += __shfl_xor(l1, 16); l1 += __shfl_xor(l1, 32);
        unsigned short* oX = s ? oB : oA;
        float* lX = s ? lB : lA;
        const int q2 = q0 - 2048;   // qt >= 64 -> rows 2048+
        if (quad == 0) {
            lX[h * 2048 + q2 + l15]      = l0;
            lX[h * 2048 + q2 + 16 + l15] = l1;
        }
        #pragma unroll
        for (int r = 0; r < 4; ++r) {
            const int qa2 = q2 + quad * 4 + r;
            #pragma unroll
            for (int nt = 0; nt < 4; ++nt) {
                oX[((size_t)h * 2048 + qa2) * 64 + nt * 16 + l15]        = f2bf(o[0][nt][r]);
                oX[((size_t)h * 2048 + qa2 + 16) * 64 + nt * 16 + l15]   = f2bf(o[1][nt][r]);
            }
        }
    } else {
        // solo: complete l across quads, transpose via per-wave LDS, write y
        float l0 = lp[0], l1 = lp[1];
        l0 += __shfl_xor(l0, 16); l0 += __shfl_xor(l0, 32);
        l1 += __shfl_xor(l1, 16); l1 += __shfl_xor(l1, 32);
        float* Lb = (float*)&Ps[w][0];
        if (quad == 0) { Lb[l15] = l0; Lb[16 + l15] = l1; }
        __syncthreads();
        f32x4 lv0 = *(const f32x4*)&Lb[quad * 4];
        f32x4 lv1 = *(const f32x4*)&Lb[16 + quad * 4];
        #pragma unroll
        for (int r = 0; r < 4; ++r) {
            const float i0 = 1.0f / lv0[r];
            const float i1 = 1.0f / lv1[r];
            const int qa = q0 + quad * 4 + r;
            const int qb = qa + 16;
            #pragma unroll
            for (int nt = 0; nt < 4; ++nt) {
                ybf[(size_t)qa * D + h * HD + nt * 16 + l15] = f2bf(o[0][nt][r] * i0);
                ybf[(size_t)qb * D + h * HD + nt * 16 + l15] = f2bf(o[1][nt][r] * i1);
            }
        }
    }
}

// ---------------------------------------------------------------------------
// merge the two key-half partials for q rows 2048+ and write bf16 y
// ---------------------------------------------------------------------------
__global__ __launch_bounds__(256)
void merge_tail(const unsigned short* __restrict__ oA,
                const unsigned short* __restrict__ oB,
                const float* __restrict__ lA, const float* __restrict__ lB,
                unsigned short* __restrict__ ybf)
{
    const int i = (blockIdx.x * 256 + threadIdx.x) * 4;   // over 16*2048*64
    const int d0 = i & 63;
    const int q2 = (i >> 6) & 2047;
    const int h  = i >> 17;
    ushort4 a = *(const ushort4*)(oA + i);
    ushort4 b = *(const ushort4*)(oB + i);
    const float linv = 1.0f / (lA[h * 2048 + q2] + lB[h * 2048 + q2]);
    ushort4 y;
    y.x = f2bf((bf2f(a.x) + bf2f(b.x)) * linv);
    y.y = f2bf((bf2f(a.y) + bf2f(b.y)) * linv);
    y.z = f2bf((bf2f(a.z) + bf2f(b.z)) * linv);
    y.w = f2bf((bf2f(a.w) + bf2f(b.w)) * linv);
    *(ushort4*)(ybf + (size_t)(2048 + q2) * D + h * 64 + d0) = y;
}

// ---------------------------------------------------------------------------
extern "C" void kernel_launch(void* const* d_in, const int* in_sizes, int n_in,
                              void* d_out, int out_size, void* d_ws, size_t ws_size,
                              hipStream_t stream)
{
    const float* x      = (const float*)d_in[0];   // [1, 4096, 1024]
    const float* w_qkv  = (const float*)d_in[1];   // [1536, 1024]
    const float* w_proj = (const float*)d_in[2];   // [1024, 1024]
    const float* q_gain = (const float*)d_in[3];   // [16]
    float* out = (float*)d_out;                    // [4096, 1024]

    // workspace layout (bf16)
    unsigned short* qbf = (unsigned short*)d_ws;              // 4M
    unsigned short* kbf = qbf + (size_t)H * Tq * HD;          // 1M
    unsigned short* vbf = kbf + (size_t)HKV * Tq * HD;        // 1M
    unsigned short* ybf = vbf + (size_t)HKV * Tq * HD;        // 4M
    unsigned short* xbf = ybf + (size_t)Tq * D;               // 4M
    unsigned short* wqkvbf  = xbf + (size_t)Tq * D;           // 1.5M
    unsigned short* wprojbf = wqkvbf + (size_t)NQKV * D;      // 1M

    // attention partial buffers ALIAS the xbf/wqkvbf region (dead after
    // gemm_qkv): oA/oB bf16 [16][2048][64] + lA/lB f32 [16][2048] = 8.65 MB
    // inside the 11 MB dead region.
    unsigned short* oA = xbf;
    float* lA = (float*)(oA + (size_t)16 * 2048 * 64);
    unsigned short* oB = (unsigned short*)(lA + 16 * 2048);
    float* lB = (float*)(oB + (size_t)16 * 2048 * 64);

    const int NTOT = Tq * D + NQKV * D + D * D;
    to_bf16_all<<<dim3(NTOT / 1024), 256, 0, stream>>>(x, w_qkv, w_proj,
                                                       xbf, wqkvbf, wprojbf);

    gemm_qkv_mfma<<<dim3(Tq / 128, NQKV / 128), 256, 0, stream>>>(xbf, wqkvbf, qbf, kbf, vbf);
    norm_rope<<<dim3((H + HKV) * Tq / 4), 256, 0, stream>>>(qbf, kbf, q_gain);
    attn_mfma<<<dim3(256, 3), 256, 0, stream>>>(qbf, kbf, vbf, ybf, oA, oB, lA, lB);
    merge_tail<<<dim3(16 * 2048 * 64 / 1024), 256, 0, stream>>>(oA, oB, lA, lB, ybf);
    gemm_proj_mfma<<<dim3(Tq / 128, D / 128), 256, 0, stream>>>(ybf, wprojbf, out);
}